// Round 1
// baseline (803.510 us; speedup 1.0000x reference)
//
#include <hip/hip_runtime.h>
#include <cmath>

// Problem constants (fixed by the reference).
constexpr int P  = 2000, M = 150, DG = 2000, F = 256, H = 4, DH = 64;
constexpr int N1 = P + M;          // 2150
constexpr int N2 = P + DG;         // 4000
constexpr int E1 = 137600, E2 = 256000, EGP = 64000, EGM = 4800;
constexpr int SA_HID = 128;

// ---------------------------------------------------------------------------
// CSR build: histogram -> single-block exclusive scan -> scatter (edge ids).
// ---------------------------------------------------------------------------
__global__ void k_hist(const int* __restrict__ idx, int* __restrict__ cnt, int E) {
  int i = blockIdx.x * 256 + threadIdx.x;
  if (i < E) atomicAdd(&cnt[idx[i]], 1);
}

__global__ void k_scan(const int* __restrict__ cnt, int* __restrict__ off,
                       int* __restrict__ cur, int n) {
  __shared__ int part[256];
  int t = threadIdx.x;
  int chunk = (n + 255) >> 8;           // per-thread contiguous chunk
  int base = t * chunk;
  int s = 0;
  for (int i = 0; i < chunk; ++i) { int id = base + i; if (id < n) s += cnt[id]; }
  part[t] = s;
  __syncthreads();
  for (int d = 1; d < 256; d <<= 1) {   // Hillis-Steele inclusive scan of partials
    int v = (t >= d) ? part[t - d] : 0;
    __syncthreads();
    part[t] += v;
    __syncthreads();
  }
  int run = (t == 0) ? 0 : part[t - 1];
  for (int i = 0; i < chunk; ++i) {
    int id = base + i;
    if (id < n) { off[id] = run; cur[id] = run; run += cnt[id]; }
  }
  if (t == 0) off[n] = part[255];
}

__global__ void k_scatter(const int* __restrict__ idx, int* __restrict__ cur,
                          int* __restrict__ eid, int E) {
  int i = blockIdx.x * 256 + threadIdx.x;
  if (i < E) { int p = atomicAdd(&cur[idx[i]], 1); eid[p] = i; }
}

// ---------------------------------------------------------------------------
// Init: lat1 = concat(pEmbed, mEmbed); lat2 = concat(pEmbed, dEmbed); acc = 0.
// ---------------------------------------------------------------------------
__global__ void k_init(const float* __restrict__ pE, const float* __restrict__ mE,
                       const float* __restrict__ dE,
                       float* __restrict__ lat1, float* __restrict__ lat2,
                       float* __restrict__ acc1, float* __restrict__ acc2) {
  int i = blockIdx.x * 256 + threadIdx.x;
  if (i < N1 * F) {
    int r = i >> 8;   // F == 256
    lat1[i] = (r < P) ? pE[i] : mE[i - P * F];
    acc1[i] = 0.f;
  }
  if (i < N2 * F) {
    int r = i >> 8;
    lat2[i] = (r < P) ? pE[i] : dE[i - P * F];
    acc2[i] = 0.f;
  }
}

// ---------------------------------------------------------------------------
// Row-parallel SPMM fused with leaky_relu(0.5) and acc += lat. Atomic-free.
// Block = one output row, 256 threads = one feature each.
// ---------------------------------------------------------------------------
__global__ void k_spmm_row(const int* __restrict__ off, const int* __restrict__ eid,
                           const int* __restrict__ cols, const float* __restrict__ vals,
                           const float* __restrict__ x, float* __restrict__ lat,
                           float* __restrict__ acc) {
  int row = blockIdx.x, t = threadIdx.x;
  int beg = off[row], end = off[row + 1];
  float s = 0.f;
  for (int i = beg; i < end; ++i) {
    int e = eid[i];
    s += vals[e] * x[(size_t)cols[e] * F + t];
  }
  s = s > 0.f ? s : 0.5f * s;           // leaky_relu slope 0.5
  size_t o = (size_t)row * F + t;
  lat[o] = s;
  acc[o] += s;
}

// ---------------------------------------------------------------------------
// GAT stage 1: feat = h @ W (n x 256), el/er head-dot reductions.
// Block handles FEAT_R rows to amortize W traffic; thread t owns output col t.
// ---------------------------------------------------------------------------
constexpr int FEAT_R = 8;
__global__ void k_gat_feat(const float* __restrict__ h, const float* __restrict__ W,
                           const float* __restrict__ al, const float* __restrict__ ar,
                           float* __restrict__ feat, float* __restrict__ el,
                           float* __restrict__ er, int n) {
  __shared__ float hs[FEAT_R][F];
  int t = threadIdx.x;
  int r0 = blockIdx.x * FEAT_R;
  for (int r = 0; r < FEAT_R; ++r) {
    int row = r0 + r;
    hs[r][t] = (row < n) ? h[(size_t)row * F + t] : 0.f;
  }
  __syncthreads();
  float acc[FEAT_R];
#pragma unroll
  for (int r = 0; r < FEAT_R; ++r) acc[r] = 0.f;
  for (int k = 0; k < F; ++k) {
    float wv = W[(size_t)k * F + t];
#pragma unroll
    for (int r = 0; r < FEAT_R; ++r) acc[r] += hs[r][k] * wv;
  }
  int head = t >> 6, d = t & 63;        // wave w == head w (64 lanes)
  float av = al[head * DH + d], rv = ar[head * DH + d];
  for (int r = 0; r < FEAT_R; ++r) {
    int row = r0 + r;
    if (row >= n) break;                // block-uniform
    feat[(size_t)row * F + t] = acc[r];
    float cl = acc[r] * av, cr = acc[r] * rv;
#pragma unroll
    for (int o = 32; o > 0; o >>= 1) {
      cl += __shfl_down(cl, o, 64);
      cr += __shfl_down(cr, o, 64);
    }
    if (d == 0) { el[row * H + head] = cl; er[row * H + head] = cr; }
  }
}

// ---------------------------------------------------------------------------
// GAT stage 2 (fused): per-dst softmax over incoming edges + aggregation +
// bias + ELU. Since out = (Σ ex*feat)/(Σ ex + 1e-9), no alpha materialization.
// Block = one dst row; thread t = feature t; head = t>>6.
// ---------------------------------------------------------------------------
__global__ void k_gat_agg(const int* __restrict__ off, const int* __restrict__ eid,
                          const int* __restrict__ gsrc,
                          const float* __restrict__ el, const float* __restrict__ er,
                          const float* __restrict__ feat, const float* __restrict__ b,
                          float* __restrict__ eout) {
  int row = blockIdx.x, t = threadIdx.x;
  int head = t >> 6;
  int beg = off[row], end = off[row + 1];
  float erv = er[row * H + head];
  float mx = -3.4e38f;
  for (int i = beg; i < end; ++i) {
    int s = gsrc[eid[i]];
    float e = el[s * H + head] + erv;
    e = e > 0.f ? e : 0.2f * e;         // leaky_relu 0.2
    mx = fmaxf(mx, e);
  }
  float ssum = 0.f, acc = 0.f;
  for (int i = beg; i < end; ++i) {
    int s = gsrc[eid[i]];
    float e = el[s * H + head] + erv;
    e = e > 0.f ? e : 0.2f * e;
    float ex = expf(e - mx);
    ssum += ex;
    acc += ex * feat[(size_t)s * F + t];
  }
  float v = acc / (ssum + 1e-9f) + b[t];
  eout[(size_t)row * F + t] = v > 0.f ? v : expm1f(v);   // ELU(alpha=1)
}

// ---------------------------------------------------------------------------
// Semantic attention: w[v] = Σ_rows tanh(z_v @ W1 + b1) @ W2  (mean applied later)
// Block = SEM_R rows of one view; 128 threads = hidden units.
// ---------------------------------------------------------------------------
constexpr int SEM_R = 8;
__global__ void k_sem_w(const float* __restrict__ z0, const float* __restrict__ z1,
                        const float* __restrict__ W1, const float* __restrict__ b1,
                        const float* __restrict__ W2, float* __restrict__ w, int n) {
  int nb = gridDim.x >> 1;
  int v = blockIdx.x / nb;
  int rb = blockIdx.x % nb;
  const float* z = v ? z1 : z0;
  __shared__ float zs[SEM_R][F];
  int t = threadIdx.x;                  // 128 threads
  int r0 = rb * SEM_R;
  for (int r = 0; r < SEM_R; ++r) {
    int row = r0 + r;
    zs[r][t]       = (row < n) ? z[(size_t)row * F + t]       : 0.f;
    zs[r][t + 128] = (row < n) ? z[(size_t)row * F + t + 128] : 0.f;
  }
  __syncthreads();
  float hid[SEM_R];
#pragma unroll
  for (int r = 0; r < SEM_R; ++r) hid[r] = b1[t];
  for (int k = 0; k < F; ++k) {
    float wv = W1[(size_t)k * SA_HID + t];
#pragma unroll
    for (int r = 0; r < SEM_R; ++r) hid[r] += zs[r][k] * wv;
  }
  float w2 = W2[t];
  float local = 0.f;
  for (int r = 0; r < SEM_R; ++r) {
    int row = r0 + r;
    if (row < n) local += tanhf(hid[r]) * w2;
  }
#pragma unroll
  for (int o = 32; o > 0; o >>= 1) local += __shfl_down(local, o, 64);
  __shared__ float ps[2];
  if ((t & 63) == 0) ps[t >> 6] = local;
  __syncthreads();
  if (t == 0) atomicAdd(&w[v], ps[0] + ps[1]);
}

// out = beta0*z0 + beta1*z1 where beta = softmax(w / n) over the 2 views.
__global__ void k_sem_combine(const float* __restrict__ z0, const float* __restrict__ z1,
                              const float* __restrict__ w, float* __restrict__ out,
                              float inv_n) {
  int i = blockIdx.x * 256 + threadIdx.x;
  float m0 = w[0] * inv_n, m1 = w[1] * inv_n;
  float mx = fmaxf(m0, m1);
  float a0 = expf(m0 - mx), a1 = expf(m1 - mx);
  float inv = 1.f / (a0 + a1);
  out[i] = (a0 * z0[i] + a1 * z1[i]) * inv;
}

// ---------------------------------------------------------------------------
// c[m2] = (Σ_m relu(med[m,:])) · W_bot[:,m2] + M*out_b[m2]   (single block)
// ---------------------------------------------------------------------------
__global__ void k_cvec(const float* __restrict__ med, const float* __restrict__ outW,
                       const float* __restrict__ outb, float* __restrict__ c) {
  __shared__ float sv[F];
  int t = threadIdx.x;                  // 256 threads
  float a = 0.f;
  for (int m = 0; m < M; ++m) { float v = med[(size_t)m * F + t]; a += v > 0.f ? v : 0.f; }
  sv[t] = a;
  __syncthreads();
  if (t < M) {
    float cc = (float)M * outb[t];
    for (int f = 0; f < F; ++f) cc += sv[f] * outW[(size_t)(F + f) * M + t];
    c[t] = cc;
  }
}

// simi_pm[p,m2] = M * relu(patient[p]) · W_top[:,m2] + c[m2]
constexpr int FIN_R = 8;                 // P % FIN_R == 0
__global__ void k_final(const float* __restrict__ patient, const float* __restrict__ outW,
                        const float* __restrict__ c, float* __restrict__ simi) {
  __shared__ float psh[FIN_R][F];
  int t = threadIdx.x;
  int r0 = blockIdx.x * FIN_R;
  for (int r = 0; r < FIN_R; ++r) {
    float v = patient[(size_t)(r0 + r) * F + t];
    psh[r][t] = v > 0.f ? v : 0.f;
  }
  __syncthreads();
  if (t < M) {
    float acc[FIN_R];
#pragma unroll
    for (int r = 0; r < FIN_R; ++r) acc[r] = 0.f;
    for (int f = 0; f < F; ++f) {
      float wv = outW[(size_t)f * M + t];
#pragma unroll
      for (int r = 0; r < FIN_R; ++r) acc[r] += psh[r][f] * wv;
    }
    float cv = c[t];
    for (int r = 0; r < FIN_R; ++r)
      simi[(size_t)(r0 + r) * M + t] = (float)M * acc[r] + cv;
  }
}

// ---------------------------------------------------------------------------
extern "C" void kernel_launch(void* const* d_in, const int* in_sizes, int n_in,
                              void* d_out, int out_size, void* d_ws, size_t ws_size,
                              hipStream_t stream) {
  const int*   adj1_rows = (const int*)d_in[0];
  const int*   adj1_cols = (const int*)d_in[1];
  const float* adj1_vals = (const float*)d_in[2];
  const int*   adj2_rows = (const int*)d_in[3];
  const int*   adj2_cols = (const int*)d_in[4];
  const float* adj2_vals = (const float*)d_in[5];
  const int*   g0_src = (const int*)d_in[6];
  const int*   g0_dst = (const int*)d_in[7];
  const int*   g1_src = (const int*)d_in[8];
  const int*   g1_dst = (const int*)d_in[9];
  const int*   g2_src = (const int*)d_in[10];
  const int*   g2_dst = (const int*)d_in[11];
  const int*   g3_src = (const int*)d_in[12];
  const int*   g3_dst = (const int*)d_in[13];
  // d_in[14] = keepRate (unused, == 1)
  const float* pE     = (const float*)d_in[15];
  const float* mE     = (const float*)d_in[16];
  const float* dE     = (const float*)d_in[17];
  const float* gat_W  = (const float*)d_in[18];
  const float* gat_al = (const float*)d_in[19];
  const float* gat_ar = (const float*)d_in[20];
  const float* gat_b  = (const float*)d_in[21];
  const float* sa_W1  = (const float*)d_in[22];
  const float* sa_b1  = (const float*)d_in[23];
  const float* sa_W2  = (const float*)d_in[24];
  const float* out_W  = (const float*)d_in[25];
  const float* out_b  = (const float*)d_in[26];

  // ---- workspace layout (floats then ints), ~28 MB total ----
  float* ws    = (float*)d_ws;
  float* latA1 = ws;
  float* latB1 = latA1 + (size_t)N1 * F;
  float* acc1  = latB1 + (size_t)N1 * F;
  float* latA2 = acc1  + (size_t)N1 * F;
  float* latB2 = latA2 + (size_t)N2 * F;
  float* acc2  = latB2 + (size_t)N2 * F;
  float* feat  = acc2  + (size_t)N2 * F;   // P*F (reused across GATs)
  float* el    = feat  + (size_t)P * F;    // P*H
  float* er    = el    + (size_t)P * H;
  float* e0b   = er    + (size_t)P * H;    // P*F
  float* e1b   = e0b   + (size_t)P * F;
  float* e2b   = e1b   + (size_t)P * F;    // M*F
  float* e3b   = e2b   + (size_t)M * F;
  float* wbuf  = e3b   + (size_t)M * F;    // 4 floats (wP[2], wM[2])
  float* cbuf  = wbuf  + 64;               // M (padded)

  int* ip   = (int*)(cbuf + 256);
  int* cnt1 = ip;            // N1
  int* cnt2 = cnt1 + N1;     // N2
  int* cg0  = cnt2 + N2;     // P
  int* cg1  = cg0 + P;
  int* cg2  = cg1 + P;       // M
  int* cg3  = cg2 + M;
  const int CNT_TOTAL = N1 + N2 + 2 * P + 2 * M;
  int* off1  = cg3 + M;      int* cur1  = off1 + N1 + 1;  int* eid1  = cur1 + N1;
  int* off2  = eid1 + E1;    int* cur2  = off2 + N2 + 1;  int* eid2  = cur2 + N2;
  int* offg0 = eid2 + E2;    int* curg0 = offg0 + P + 1;  int* eidg0 = curg0 + P;
  int* offg1 = eidg0 + EGP;  int* curg1 = offg1 + P + 1;  int* eidg1 = curg1 + P;
  int* offg2 = eidg1 + EGP;  int* curg2 = offg2 + M + 1;  int* eidg2 = curg2 + M;
  int* offg3 = eidg2 + EGM;  int* curg3 = offg3 + M + 1;  int* eidg3 = curg3 + M;

  // ---- output layout: (simi_pm, d_gcn, med, m_gcn, patient) ----
  float* out_simi = (float*)d_out;               // P*M
  float* out_dgcn = out_simi + (size_t)P * M;    // DG*F
  float* out_med  = out_dgcn + (size_t)DG * F;   // M*F
  float* out_mgcn = out_med  + (size_t)M * F;    // M*F
  float* out_pat  = out_mgcn + (size_t)M * F;    // P*F

  // ---- init + zero ----
  k_init<<<(N2 * F + 255) / 256, 256, 0, stream>>>(pE, mE, dE, latA1, latA2, acc1, acc2);
  hipMemsetAsync(cnt1, 0, (size_t)CNT_TOTAL * 4, stream);
  hipMemsetAsync(wbuf, 0, 16, stream);

  // ---- CSR builds (adj by row; gat graphs by dst) ----
  auto build = [&](const int* idx, int n, int E, int* cnt, int* off, int* cur, int* eid) {
    k_hist<<<(E + 255) / 256, 256, 0, stream>>>(idx, cnt, E);
    k_scan<<<1, 256, 0, stream>>>(cnt, off, cur, n);
    k_scatter<<<(E + 255) / 256, 256, 0, stream>>>(idx, cur, eid, E);
  };
  build(adj1_rows, N1, E1, cnt1, off1, cur1, eid1);
  build(adj2_rows, N2, E2, cnt2, off2, cur2, eid2);
  build(g0_dst, P, EGP, cg0, offg0, curg0, eidg0);
  build(g1_dst, P, EGP, cg1, offg1, curg1, eidg1);
  build(g2_dst, M, EGM, cg2, offg2, curg2, eidg2);
  build(g3_dst, M, EGM, cg3, offg3, curg3, eidg3);

  // ---- GNN: 2 layers, double-buffered lat, fused lrelu + acc ----
  k_spmm_row<<<N1, 256, 0, stream>>>(off1, eid1, adj1_cols, adj1_vals, latA1, latB1, acc1);
  k_spmm_row<<<N2, 256, 0, stream>>>(off2, eid2, adj2_cols, adj2_vals, latA2, latB2, acc2);
  k_spmm_row<<<N1, 256, 0, stream>>>(off1, eid1, adj1_cols, adj1_vals, latB1, latA1, acc1);
  k_spmm_row<<<N2, 256, 0, stream>>>(off2, eid2, adj2_cols, adj2_vals, latB2, latA2, acc2);

  // d_gcn = acc2[P:], m_gcn = acc1[P:]
  hipMemcpyAsync(out_dgcn, acc2 + (size_t)P * F, (size_t)DG * F * 4,
                 hipMemcpyDeviceToDevice, stream);
  hipMemcpyAsync(out_mgcn, acc1 + (size_t)P * F, (size_t)M * F * 4,
                 hipMemcpyDeviceToDevice, stream);

  // ---- 4 GATs (feat/el/er scratch reused serially) ----
  // gat0: h = p1 = acc1[:P]
  k_gat_feat<<<(P + FEAT_R - 1) / FEAT_R, 256, 0, stream>>>(
      acc1, gat_W + 0 * F * F, gat_al + 0 * H * DH, gat_ar + 0 * H * DH, feat, el, er, P);
  k_gat_agg<<<P, 256, 0, stream>>>(offg0, eidg0, g0_src, el, er, feat, gat_b + 0 * F, e0b);
  // gat1: h = p2 = acc2[:P]
  k_gat_feat<<<(P + FEAT_R - 1) / FEAT_R, 256, 0, stream>>>(
      acc2, gat_W + 1 * F * F, gat_al + 1 * H * DH, gat_ar + 1 * H * DH, feat, el, er, P);
  k_gat_agg<<<P, 256, 0, stream>>>(offg1, eidg1, g1_src, el, er, feat, gat_b + 1 * F, e1b);
  // gat2: h = m_gcn = acc1[P:]
  k_gat_feat<<<(M + FEAT_R - 1) / FEAT_R, 256, 0, stream>>>(
      acc1 + (size_t)P * F, gat_W + 2 * F * F, gat_al + 2 * H * DH, gat_ar + 2 * H * DH,
      feat, el, er, M);
  k_gat_agg<<<M, 256, 0, stream>>>(offg2, eidg2, g2_src, el, er, feat, gat_b + 2 * F, e2b);
  // gat3: h = m_gcn
  k_gat_feat<<<(M + FEAT_R - 1) / FEAT_R, 256, 0, stream>>>(
      acc1 + (size_t)P * F, gat_W + 3 * F * F, gat_al + 3 * H * DH, gat_ar + 3 * H * DH,
      feat, el, er, M);
  k_gat_agg<<<M, 256, 0, stream>>>(offg3, eidg3, g3_src, el, er, feat, gat_b + 3 * F, e3b);

  // ---- semantic attention: patient (e0,e1) and med (e2,e3) ----
  {
    int nb = (P + SEM_R - 1) / SEM_R;
    k_sem_w<<<2 * nb, 128, 0, stream>>>(e0b, e1b, sa_W1, sa_b1, sa_W2, wbuf, P);
    k_sem_combine<<<P, 256, 0, stream>>>(e0b, e1b, wbuf, out_pat, 1.f / P);
  }
  {
    int nb = (M + SEM_R - 1) / SEM_R;
    k_sem_w<<<2 * nb, 128, 0, stream>>>(e2b, e3b, sa_W1, sa_b1, sa_W2, wbuf + 2, M);
    k_sem_combine<<<M, 256, 0, stream>>>(e2b, e3b, wbuf + 2, out_med, 1.f / M);
  }

  // ---- final: simi_pm = M * relu(patient) @ W_top + c ----
  k_cvec<<<1, 256, 0, stream>>>(out_med, out_W, out_b, cbuf);
  k_final<<<P / FIN_R, 256, 0, stream>>>(out_pat, out_W, cbuf, out_simi);
}

// Round 2
// 364.373 us; speedup vs baseline: 2.2052x; 2.2052x over previous
//
#include <hip/hip_runtime.h>
#include <cmath>
#include <cstdint>

// Problem constants (fixed by the reference).
constexpr int P  = 2000, M = 150, DG = 2000, F = 256, H = 4, DH = 64;
constexpr int N1 = P + M;          // 2150
constexpr int N2 = P + DG;         // 4000
constexpr int E1 = 137600, E2 = 256000, EGP = 64000, EGM = 4800;
constexpr int SA_HID = 128;

// Edge-range offsets for the fused hist/scatter kernels.
constexpr int HO1 = E1, HO2 = E1 + E2, HO3 = HO2 + EGP, HO4 = HO3 + EGP,
              HO5 = HO4 + EGM, HOE = HO5 + EGM;   // 531200 total edges

// ---------------------------------------------------------------------------
// Fused histogram over all 6 graphs.
// ---------------------------------------------------------------------------
__global__ void k_hist_all(const int* __restrict__ a1r, const int* __restrict__ a2r,
                           const int* __restrict__ d0, const int* __restrict__ d1,
                           const int* __restrict__ d2, const int* __restrict__ d3,
                           int* __restrict__ c1, int* __restrict__ c2,
                           int* __restrict__ cg0, int* __restrict__ cg1,
                           int* __restrict__ cg2, int* __restrict__ cg3) {
  int i = blockIdx.x * 256 + threadIdx.x;
  if (i >= HOE) return;
  if (i < HO1)      atomicAdd(&c1[a1r[i]], 1);
  else if (i < HO2) atomicAdd(&c2[a2r[i - HO1]], 1);
  else if (i < HO3) atomicAdd(&cg0[d0[i - HO2]], 1);
  else if (i < HO4) atomicAdd(&cg1[d1[i - HO3]], 1);
  else if (i < HO5) atomicAdd(&cg2[d2[i - HO4]], 1);
  else              atomicAdd(&cg3[d3[i - HO5]], 1);
}

// ---------------------------------------------------------------------------
// Fused exclusive scan: block b scans graph b (n <= 4000, 256 threads).
// ---------------------------------------------------------------------------
struct ScanArgs { const int* cnt[6]; int* off[6]; int* cur[6]; int n[6]; };

__global__ void k_scan_all(ScanArgs a) {
  int b = blockIdx.x;
  const int* cnt = a.cnt[b]; int* off = a.off[b]; int* cur = a.cur[b]; int n = a.n[b];
  __shared__ int part[256];
  int t = threadIdx.x;
  int chunk = (n + 255) >> 8;
  int base = t * chunk;
  int s = 0;
  for (int i = 0; i < chunk; ++i) { int id = base + i; if (id < n) s += cnt[id]; }
  part[t] = s;
  __syncthreads();
  for (int d = 1; d < 256; d <<= 1) {
    int v = (t >= d) ? part[t - d] : 0;
    __syncthreads();
    part[t] += v;
    __syncthreads();
  }
  int run = (t == 0) ? 0 : part[t - 1];
  for (int i = 0; i < chunk; ++i) {
    int id = base + i;
    if (id < n) { off[id] = run; cur[id] = run; run += cnt[id]; }
  }
  if (t == 0) off[n] = part[255];
}

// ---------------------------------------------------------------------------
// Fused scatter: stores PERMUTED payloads (col/val for adj, src for gat) so
// SPMM/GAT loops have one fewer indirection and sequential metadata reads.
// ---------------------------------------------------------------------------
__global__ void k_scat_all(const int* __restrict__ a1r, const int* __restrict__ a1c,
                           const float* __restrict__ a1v,
                           const int* __restrict__ a2r, const int* __restrict__ a2c,
                           const float* __restrict__ a2v,
                           const int* __restrict__ d0, const int* __restrict__ s0,
                           const int* __restrict__ d1, const int* __restrict__ s1,
                           const int* __restrict__ d2, const int* __restrict__ s2,
                           const int* __restrict__ d3, const int* __restrict__ s3,
                           int* cur1, int* pc1, float* pv1,
                           int* cur2, int* pc2, float* pv2,
                           int* cu0, int* ps0, int* cu1, int* ps1,
                           int* cu2, int* ps2, int* cu3, int* ps3) {
  int i = blockIdx.x * 256 + threadIdx.x;
  if (i >= HOE) return;
  if (i < HO1) {
    int p = atomicAdd(&cur1[a1r[i]], 1); pc1[p] = a1c[i]; pv1[p] = a1v[i];
  } else if (i < HO2) {
    int j = i - HO1;
    int p = atomicAdd(&cur2[a2r[j]], 1); pc2[p] = a2c[j]; pv2[p] = a2v[j];
  } else if (i < HO3) {
    int j = i - HO2; int p = atomicAdd(&cu0[d0[j]], 1); ps0[p] = s0[j];
  } else if (i < HO4) {
    int j = i - HO3; int p = atomicAdd(&cu1[d1[j]], 1); ps1[p] = s1[j];
  } else if (i < HO5) {
    int j = i - HO4; int p = atomicAdd(&cu2[d2[j]], 1); ps2[p] = s2[j];
  } else {
    int j = i - HO5; int p = atomicAdd(&cu3[d3[j]], 1); ps3[p] = s3[j];
  }
}

// ---------------------------------------------------------------------------
// SPMM: wave-per-row, float4 per lane (64*16B = full 1KB row), unroll-4.
// LAYER 1: x = embeds (read directly, no init kernel), writes lat only.
// LAYER 2: x = lat, writes acc = lat[row] + s, plus m_gcn/d_gcn output slices.
// Both graphs in one dispatch (waves [0,N1) = graph1, [N1,N1+N2) = graph2).
// ---------------------------------------------------------------------------
template<int LAYER>
__global__ __launch_bounds__(256) void k_spmm(
    const int* __restrict__ off1, const int* __restrict__ pc1, const float* __restrict__ pv1,
    const int* __restrict__ off2, const int* __restrict__ pc2, const float* __restrict__ pv2,
    const float* __restrict__ pE, const float* __restrict__ mE, const float* __restrict__ dE,
    float* __restrict__ lat1, float* __restrict__ lat2,
    float* __restrict__ acc1, float* __restrict__ acc2,
    float* __restrict__ out_mgcn, float* __restrict__ out_dgcn) {
  int gw = (blockIdx.x * 256 + threadIdx.x) >> 6;
  if (gw >= N1 + N2) return;
  int lane = threadIdx.x & 63;
  bool g2 = gw >= N1;
  int row = g2 ? gw - N1 : gw;
  const int*   off = g2 ? off2 : off1;
  const int*   pc  = g2 ? pc2  : pc1;
  const float* pv  = g2 ? pv2  : pv1;
  const float* latin = g2 ? lat2 : lat1;
  const float* tailE = g2 ? dE : mE;
  int beg = off[row], end = off[row + 1];
  int fo = lane << 2;
  float4 s = {0.f, 0.f, 0.f, 0.f};
  auto fetch = [&](int c) -> float4 {
    const float* b;
    if (LAYER == 1) b = (c < P) ? (pE + (size_t)c * F) : (tailE + (size_t)(c - P) * F);
    else            b = latin + (size_t)c * F;
    return *(const float4*)(b + fo);
  };
  int i = beg;
  for (; i + 4 <= end; i += 4) {
    int c0 = pc[i], c1 = pc[i + 1], c2 = pc[i + 2], c3 = pc[i + 3];
    float v0 = pv[i], v1 = pv[i + 1], v2 = pv[i + 2], v3 = pv[i + 3];
    float4 a0 = fetch(c0), a1 = fetch(c1), a2 = fetch(c2), a3 = fetch(c3);
    s.x += v0 * a0.x + v1 * a1.x + v2 * a2.x + v3 * a3.x;
    s.y += v0 * a0.y + v1 * a1.y + v2 * a2.y + v3 * a3.y;
    s.z += v0 * a0.z + v1 * a1.z + v2 * a2.z + v3 * a3.z;
    s.w += v0 * a0.w + v1 * a1.w + v2 * a2.w + v3 * a3.w;
  }
  for (; i < end; ++i) {
    int c = pc[i]; float v = pv[i];
    float4 a = fetch(c);
    s.x += v * a.x; s.y += v * a.y; s.z += v * a.z; s.w += v * a.w;
  }
  float4 l;
  l.x = s.x > 0.f ? s.x : 0.5f * s.x;
  l.y = s.y > 0.f ? s.y : 0.5f * s.y;
  l.z = s.z > 0.f ? s.z : 0.5f * s.z;
  l.w = s.w > 0.f ? s.w : 0.5f * s.w;
  if (LAYER == 1) {
    *(float4*)((g2 ? lat2 : lat1) + (size_t)row * F + fo) = l;
  } else {
    float4 b = *(const float4*)(latin + (size_t)row * F + fo);  // acc after L1 == lat1
    float4 a = {b.x + l.x, b.y + l.y, b.z + l.z, b.w + l.w};
    *(float4*)((g2 ? acc2 : acc1) + (size_t)row * F + fo) = a;
    if (row >= P)
      *(float4*)((g2 ? out_dgcn : out_mgcn) + (size_t)(row - P) * F + fo) = a;
  }
}

// ---------------------------------------------------------------------------
// All 4 GAT feature GEMMs in one dispatch. FR=4 rows/block, float4 LDS reads.
// ---------------------------------------------------------------------------
constexpr int FR  = 4;
constexpr int NB0 = (P + FR - 1) / FR;   // 500
constexpr int NB2 = (M + FR - 1) / FR;   // 38
constexpr int FEAT_BLOCKS = 2 * NB0 + 2 * NB2;

__global__ __launch_bounds__(256) void k_gat_feat_all(
    const float* __restrict__ acc1, const float* __restrict__ acc2,
    const float* __restrict__ gat_W, const float* __restrict__ gat_al,
    const float* __restrict__ gat_ar,
    float* __restrict__ f0, float* __restrict__ f1,
    float* __restrict__ f2, float* __restrict__ f3,
    float* __restrict__ el, float* __restrict__ er) {
  int b = blockIdx.x;
  int g, rb, n; const float* h; float* fout;
  if (b < NB0)            { g = 0; rb = b;              n = P; h = acc1; fout = f0; }
  else if (b < 2 * NB0)   { g = 1; rb = b - NB0;        n = P; h = acc2; fout = f1; }
  else if (b < 2*NB0+NB2) { g = 2; rb = b - 2 * NB0;    n = M; h = acc1 + (size_t)P * F; fout = f2; }
  else                    { g = 3; rb = b - 2*NB0 - NB2; n = M; h = acc1 + (size_t)P * F; fout = f3; }
  int elo = (g == 0) ? 0 : (g == 1) ? P * H : (g == 2) ? 2 * P * H : (2 * P + M) * H;
  const float* W = gat_W + (size_t)g * F * F;
  __shared__ float hs[FR][F];
  int t = threadIdx.x;
  int r0 = rb * FR;
  {
    int r = t >> 6, ln = t & 63;
    int row = r0 + r;
    float4 v = {0.f, 0.f, 0.f, 0.f};
    if (row < n) v = *(const float4*)(h + (size_t)row * F + (ln << 2));
    *(float4*)&hs[r][ln << 2] = v;
  }
  __syncthreads();
  float acc[FR] = {0.f, 0.f, 0.f, 0.f};
  for (int k = 0; k < F; k += 4) {
    float w0 = W[(size_t)k * F + t],       w1 = W[(size_t)(k + 1) * F + t],
          w2 = W[(size_t)(k + 2) * F + t], w3 = W[(size_t)(k + 3) * F + t];
#pragma unroll
    for (int r = 0; r < FR; ++r) {
      float4 h4 = *(const float4*)&hs[r][k];
      acc[r] += h4.x * w0 + h4.y * w1 + h4.z * w2 + h4.w * w3;
    }
  }
  int head = t >> 6, d = t & 63;           // one wave == one head
  float av = gat_al[g * H * DH + head * DH + d];
  float rv = gat_ar[g * H * DH + head * DH + d];
#pragma unroll
  for (int r = 0; r < FR; ++r) {
    int row = r0 + r;
    if (row < n) {
      fout[(size_t)row * F + t] = acc[r];
      float cl = acc[r] * av, cr = acc[r] * rv;
      for (int o = 32; o > 0; o >>= 1) {
        cl += __shfl_down(cl, o, 64);
        cr += __shfl_down(cr, o, 64);
      }
      if (d == 0) { el[elo + row * H + head] = cl; er[elo + row * H + head] = cr; }
    }
  }
}

// ---------------------------------------------------------------------------
// All 4 GAT aggregations in one dispatch: wave-per-dst-row, float4 gathers,
// fused online max + exp-sum + weighted aggregation + bias + ELU.
// ---------------------------------------------------------------------------
__global__ __launch_bounds__(256) void k_gat_agg_all(
    const int* __restrict__ og0, const int* __restrict__ ps0,
    const int* __restrict__ og1, const int* __restrict__ ps1,
    const int* __restrict__ og2, const int* __restrict__ ps2,
    const int* __restrict__ og3, const int* __restrict__ ps3,
    const float* __restrict__ el, const float* __restrict__ er,
    const float* __restrict__ f0, const float* __restrict__ f1,
    const float* __restrict__ f2, const float* __restrict__ f3,
    const float* __restrict__ gat_b,
    float* __restrict__ e0, float* __restrict__ e1,
    float* __restrict__ e2, float* __restrict__ e3) {
  int gw = (blockIdx.x * 256 + threadIdx.x) >> 6;
  if (gw >= 2 * P + 2 * M) return;
  int lane = threadIdx.x & 63;
  int g, row; const int* off; const int* ps; const float* feat; float* out; int elo;
  if (gw < P)            { g = 0; row = gw;             off = og0; ps = ps0; feat = f0; out = e0; elo = 0; }
  else if (gw < 2 * P)   { g = 1; row = gw - P;         off = og1; ps = ps1; feat = f1; out = e1; elo = P * H; }
  else if (gw < 2*P + M) { g = 2; row = gw - 2 * P;     off = og2; ps = ps2; feat = f2; out = e2; elo = 2 * P * H; }
  else                   { g = 3; row = gw - 2 * P - M; off = og3; ps = ps3; feat = f3; out = e3; elo = (2 * P + M) * H; }
  int head = lane >> 4;
  int fo = lane << 2;
  const float* elb = el + elo;
  float erv = er[elo + row * H + head];
  int beg = off[row], end = off[row + 1];
  float mx = -3.4e38f;
  int i = beg;
  for (; i + 4 <= end; i += 4) {
    int s0 = ps[i], s1 = ps[i + 1], s2 = ps[i + 2], s3 = ps[i + 3];
    float a = elb[s0 * H + head] + erv, b = elb[s1 * H + head] + erv,
          c = elb[s2 * H + head] + erv, d = elb[s3 * H + head] + erv;
    a = a > 0.f ? a : 0.2f * a; b = b > 0.f ? b : 0.2f * b;
    c = c > 0.f ? c : 0.2f * c; d = d > 0.f ? d : 0.2f * d;
    mx = fmaxf(mx, fmaxf(fmaxf(a, b), fmaxf(c, d)));
  }
  for (; i < end; ++i) {
    float a = elb[ps[i] * H + head] + erv;
    a = a > 0.f ? a : 0.2f * a;
    mx = fmaxf(mx, a);
  }
  float ssum = 0.f;
  float4 acc = {0.f, 0.f, 0.f, 0.f};
  i = beg;
  for (; i + 2 <= end; i += 2) {
    int s0 = ps[i], s1 = ps[i + 1];
    float a = elb[s0 * H + head] + erv; a = a > 0.f ? a : 0.2f * a;
    float b = elb[s1 * H + head] + erv; b = b > 0.f ? b : 0.2f * b;
    float x0 = expf(a - mx), x1 = expf(b - mx);
    float4 q0 = *(const float4*)(feat + (size_t)s0 * F + fo);
    float4 q1 = *(const float4*)(feat + (size_t)s1 * F + fo);
    ssum += x0 + x1;
    acc.x += x0 * q0.x + x1 * q1.x;
    acc.y += x0 * q0.y + x1 * q1.y;
    acc.z += x0 * q0.z + x1 * q1.z;
    acc.w += x0 * q0.w + x1 * q1.w;
  }
  for (; i < end; ++i) {
    int s0 = ps[i];
    float a = elb[s0 * H + head] + erv; a = a > 0.f ? a : 0.2f * a;
    float x0 = expf(a - mx);
    float4 q0 = *(const float4*)(feat + (size_t)s0 * F + fo);
    ssum += x0;
    acc.x += x0 * q0.x; acc.y += x0 * q0.y; acc.z += x0 * q0.z; acc.w += x0 * q0.w;
  }
  float inv = 1.f / (ssum + 1e-9f);
  const float* bb = gat_b + g * F + fo;
  float4 v = {acc.x * inv + bb[0], acc.y * inv + bb[1],
              acc.z * inv + bb[2], acc.w * inv + bb[3]};
  v.x = v.x > 0.f ? v.x : expm1f(v.x);
  v.y = v.y > 0.f ? v.y : expm1f(v.y);
  v.z = v.z > 0.f ? v.z : expm1f(v.z);
  v.w = v.w > 0.f ? v.w : expm1f(v.w);
  *(float4*)(out + (size_t)row * F + fo) = v;
}

// ---------------------------------------------------------------------------
// Semantic attention weights for all 4 z-matrices in one dispatch.
// ---------------------------------------------------------------------------
constexpr int SR  = 8;
constexpr int SB0 = (P + SR - 1) / SR;   // 250
constexpr int SB2 = (M + SR - 1) / SR;   // 19
constexpr int SEM_BLOCKS = 2 * SB0 + 2 * SB2;

__global__ __launch_bounds__(128) void k_sem_w_all(
    const float* __restrict__ e0, const float* __restrict__ e1,
    const float* __restrict__ e2, const float* __restrict__ e3,
    const float* __restrict__ W1, const float* __restrict__ b1,
    const float* __restrict__ W2, float* __restrict__ w) {
  int b = blockIdx.x;
  int zid, rb, n; const float* z;
  if (b < SB0)            { zid = 0; rb = b;             n = P; z = e0; }
  else if (b < 2 * SB0)   { zid = 1; rb = b - SB0;       n = P; z = e1; }
  else if (b < 2*SB0+SB2) { zid = 2; rb = b - 2 * SB0;   n = M; z = e2; }
  else                    { zid = 3; rb = b - 2*SB0-SB2; n = M; z = e3; }
  __shared__ float zs[SR][F];
  int t = threadIdx.x;
  int r0 = rb * SR;
  for (int q = t; q < SR * 64; q += 128) {
    int r = q >> 6, ln = q & 63;
    int row = r0 + r;
    float4 v = {0.f, 0.f, 0.f, 0.f};
    if (row < n) v = *(const float4*)(z + (size_t)row * F + (ln << 2));
    *(float4*)&zs[r][ln << 2] = v;
  }
  __syncthreads();
  float hid[SR];
#pragma unroll
  for (int r = 0; r < SR; ++r) hid[r] = b1[t];
  for (int k = 0; k < F; k += 4) {
    float w0 = W1[(size_t)k * SA_HID + t],       w1 = W1[(size_t)(k + 1) * SA_HID + t],
          w2 = W1[(size_t)(k + 2) * SA_HID + t], w3 = W1[(size_t)(k + 3) * SA_HID + t];
#pragma unroll
    for (int r = 0; r < SR; ++r) {
      float4 z4 = *(const float4*)&zs[r][k];
      hid[r] += z4.x * w0 + z4.y * w1 + z4.z * w2 + z4.w * w3;
    }
  }
  float w2v = W2[t];
  float local = 0.f;
  for (int r = 0; r < SR; ++r) {
    int row = r0 + r;
    if (row < n) local += tanhf(hid[r]) * w2v;
  }
  for (int o = 32; o > 0; o >>= 1) local += __shfl_down(local, o, 64);
  __shared__ float pp[2];
  if ((t & 63) == 0) pp[t >> 6] = local;
  __syncthreads();
  if (t == 0) atomicAdd(&w[zid], pp[0] + pp[1]);
}

// Combine both groups in one dispatch: out = softmax(w/n) . {z0,z1}, float4.
__global__ void k_sem_comb_all(const float* __restrict__ e0, const float* __restrict__ e1,
                               const float* __restrict__ e2, const float* __restrict__ e3,
                               const float* __restrict__ w,
                               float* __restrict__ out_pat, float* __restrict__ out_med) {
  constexpr int Q0 = P * F / 4;       // 128000 float4s (patient)
  constexpr int QE = Q0 + M * F / 4;  // + 9600 (med)
  int i = blockIdx.x * 256 + threadIdx.x;
  if (i >= QE) return;
  const float4 *z0, *z1; float* out; float inv_n; const float* wp; int j;
  if (i < Q0) { z0 = (const float4*)e0; z1 = (const float4*)e1; out = out_pat; inv_n = 1.f / P; wp = w;     j = i; }
  else        { z0 = (const float4*)e2; z1 = (const float4*)e3; out = out_med; inv_n = 1.f / M; wp = w + 2; j = i - Q0; }
  float m0 = wp[0] * inv_n, m1 = wp[1] * inv_n;
  float mxv = fmaxf(m0, m1);
  float a0 = expf(m0 - mxv), a1 = expf(m1 - mxv);
  float s = 1.f / (a0 + a1);
  a0 *= s; a1 *= s;
  float4 u0 = z0[j], u1 = z1[j];
  float4 r = {a0 * u0.x + a1 * u1.x, a0 * u0.y + a1 * u1.y,
              a0 * u0.z + a1 * u1.z, a0 * u0.w + a1 * u1.w};
  ((float4*)out)[j] = r;
}

// ---------------------------------------------------------------------------
// c[m2] = (Σ_m relu(med[m,:])) . W_bot[:,m2] + M*out_b[m2]   (single block)
// ---------------------------------------------------------------------------
__global__ void k_cvec(const float* __restrict__ med, const float* __restrict__ outW,
                       const float* __restrict__ outb, float* __restrict__ c) {
  __shared__ float sv[F];
  int t = threadIdx.x;  // 256
  float a = 0.f;
  for (int m = 0; m < M; ++m) { float v = med[(size_t)m * F + t]; a += v > 0.f ? v : 0.f; }
  sv[t] = a;
  __syncthreads();
  if (t < M) {
    float cc = (float)M * outb[t];
    for (int f = 0; f < F; ++f) cc += sv[f] * outW[(size_t)(F + f) * M + t];
    c[t] = cc;
  }
}

// simi_pm[p,m2] = M * relu(patient[p]) . W_top[:,m2] + c[m2]
constexpr int FIN_R = 8;   // P % FIN_R == 0
__global__ __launch_bounds__(256) void k_final(const float* __restrict__ pat,
                                               const float* __restrict__ outW,
                                               const float* __restrict__ c,
                                               float* __restrict__ simi) {
  __shared__ float psh[FIN_R][F];
  int t = threadIdx.x;
  int r0 = blockIdx.x * FIN_R;
  for (int q = t; q < FIN_R * 64; q += 256) {
    int r = q >> 6, ln = q & 63;
    float4 v = *(const float4*)(pat + (size_t)(r0 + r) * F + (ln << 2));
    v.x = v.x > 0.f ? v.x : 0.f; v.y = v.y > 0.f ? v.y : 0.f;
    v.z = v.z > 0.f ? v.z : 0.f; v.w = v.w > 0.f ? v.w : 0.f;
    *(float4*)&psh[r][ln << 2] = v;
  }
  __syncthreads();
  if (t < M) {
    float acc[FIN_R];
#pragma unroll
    for (int r = 0; r < FIN_R; ++r) acc[r] = 0.f;
    for (int f = 0; f < F; f += 4) {
      float w0 = outW[(size_t)f * M + t],       w1 = outW[(size_t)(f + 1) * M + t],
            w2 = outW[(size_t)(f + 2) * M + t], w3 = outW[(size_t)(f + 3) * M + t];
#pragma unroll
      for (int r = 0; r < FIN_R; ++r) {
        float4 p4 = *(const float4*)&psh[r][f];
        acc[r] += p4.x * w0 + p4.y * w1 + p4.z * w2 + p4.w * w3;
      }
    }
    float cv = c[t];
    for (int r = 0; r < FIN_R; ++r)
      simi[(size_t)(r0 + r) * M + t] = (float)M * acc[r] + cv;
  }
}

// ---------------------------------------------------------------------------
extern "C" void kernel_launch(void* const* d_in, const int* in_sizes, int n_in,
                              void* d_out, int out_size, void* d_ws, size_t ws_size,
                              hipStream_t stream) {
  const int*   adj1_rows = (const int*)d_in[0];
  const int*   adj1_cols = (const int*)d_in[1];
  const float* adj1_vals = (const float*)d_in[2];
  const int*   adj2_rows = (const int*)d_in[3];
  const int*   adj2_cols = (const int*)d_in[4];
  const float* adj2_vals = (const float*)d_in[5];
  const int*   g0_src = (const int*)d_in[6];
  const int*   g0_dst = (const int*)d_in[7];
  const int*   g1_src = (const int*)d_in[8];
  const int*   g1_dst = (const int*)d_in[9];
  const int*   g2_src = (const int*)d_in[10];
  const int*   g2_dst = (const int*)d_in[11];
  const int*   g3_src = (const int*)d_in[12];
  const int*   g3_dst = (const int*)d_in[13];
  // d_in[14] = keepRate (unused, == 1)
  const float* pE     = (const float*)d_in[15];
  const float* mE     = (const float*)d_in[16];
  const float* dE     = (const float*)d_in[17];
  const float* gat_W  = (const float*)d_in[18];
  const float* gat_al = (const float*)d_in[19];
  const float* gat_ar = (const float*)d_in[20];
  const float* gat_b  = (const float*)d_in[21];
  const float* sa_W1  = (const float*)d_in[22];
  const float* sa_b1  = (const float*)d_in[23];
  const float* sa_W2  = (const float*)d_in[24];
  const float* out_W  = (const float*)d_in[25];
  const float* out_b  = (const float*)d_in[26];

  // ---- workspace layout ----
  int* ip = (int*)d_ws;
  int* cnt1 = ip; ip += N1;
  int* cnt2 = ip; ip += N2;
  int* cg0  = ip; ip += P;
  int* cg1  = ip; ip += P;
  int* cg2  = ip; ip += M;
  int* cg3  = ip; ip += M;
  float* wbuf = (float*)ip; ip += 4;
  size_t memset_bytes = (size_t)((char*)ip - (char*)d_ws);
  int* off1 = ip; ip += N1 + 1;  int* cur1 = ip; ip += N1;
  int* pc1  = ip; ip += E1;      float* pv1 = (float*)ip; ip += E1;
  int* off2 = ip; ip += N2 + 1;  int* cur2 = ip; ip += N2;
  int* pc2  = ip; ip += E2;      float* pv2 = (float*)ip; ip += E2;
  int* og0 = ip; ip += P + 1;  int* cu0 = ip; ip += P;  int* ps0 = ip; ip += EGP;
  int* og1 = ip; ip += P + 1;  int* cu1 = ip; ip += P;  int* ps1 = ip; ip += EGP;
  int* og2 = ip; ip += M + 1;  int* cu2 = ip; ip += M;  int* ps2 = ip; ip += EGM;
  int* og3 = ip; ip += M + 1;  int* cu3 = ip; ip += M;  int* ps3 = ip; ip += EGM;
  uintptr_t up = ((uintptr_t)ip + 15) & ~(uintptr_t)15;
  float* fp = (float*)up;
  float* lat1 = fp; fp += (size_t)N1 * F;
  float* lat2 = fp; fp += (size_t)N2 * F;
  float* acc1 = fp; fp += (size_t)N1 * F;
  float* acc2 = fp; fp += (size_t)N2 * F;
  float* f0   = fp; fp += (size_t)P * F;
  float* f1   = fp; fp += (size_t)P * F;
  float* f2   = fp; fp += (size_t)M * F;
  float* f3   = fp; fp += (size_t)M * F;
  float* el   = fp; fp += (size_t)(2 * P + 2 * M) * H;
  float* er   = fp; fp += (size_t)(2 * P + 2 * M) * H;
  float* e0b  = fp; fp += (size_t)P * F;
  float* e1b  = fp; fp += (size_t)P * F;
  float* e2b  = fp; fp += (size_t)M * F;
  float* e3b  = fp; fp += (size_t)M * F;
  float* cbuf = fp; fp += 256;

  // ---- output layout: (simi_pm, d_gcn, med, m_gcn, patient) ----
  float* out_simi = (float*)d_out;               // P*M
  float* out_dgcn = out_simi + (size_t)P * M;    // DG*F
  float* out_med  = out_dgcn + (size_t)DG * F;   // M*F
  float* out_mgcn = out_med  + (size_t)M * F;    // M*F
  float* out_pat  = out_mgcn + (size_t)M * F;    // P*F

  // ---- zero counters + wbuf (one contiguous memset) ----
  hipMemsetAsync(d_ws, 0, memset_bytes, stream);

  // ---- CSR build: 3 dispatches total ----
  int eb = (HOE + 255) / 256;
  k_hist_all<<<eb, 256, 0, stream>>>(adj1_rows, adj2_rows, g0_dst, g1_dst, g2_dst, g3_dst,
                                     cnt1, cnt2, cg0, cg1, cg2, cg3);
  ScanArgs sa;
  sa.cnt[0] = cnt1; sa.off[0] = off1; sa.cur[0] = cur1; sa.n[0] = N1;
  sa.cnt[1] = cnt2; sa.off[1] = off2; sa.cur[1] = cur2; sa.n[1] = N2;
  sa.cnt[2] = cg0;  sa.off[2] = og0;  sa.cur[2] = cu0;  sa.n[2] = P;
  sa.cnt[3] = cg1;  sa.off[3] = og1;  sa.cur[3] = cu1;  sa.n[3] = P;
  sa.cnt[4] = cg2;  sa.off[4] = og2;  sa.cur[4] = cu2;  sa.n[4] = M;
  sa.cnt[5] = cg3;  sa.off[5] = og3;  sa.cur[5] = cu3;  sa.n[5] = M;
  k_scan_all<<<6, 256, 0, stream>>>(sa);
  k_scat_all<<<eb, 256, 0, stream>>>(adj1_rows, adj1_cols, adj1_vals,
                                     adj2_rows, adj2_cols, adj2_vals,
                                     g0_dst, g0_src, g1_dst, g1_src,
                                     g2_dst, g2_src, g3_dst, g3_src,
                                     cur1, pc1, pv1, cur2, pc2, pv2,
                                     cu0, ps0, cu1, ps1, cu2, ps2, cu3, ps3);

  // ---- GNN: 2 fused layers (both graphs per dispatch) ----
  int sb = ((N1 + N2) * 64 + 255) / 256;
  k_spmm<1><<<sb, 256, 0, stream>>>(off1, pc1, pv1, off2, pc2, pv2, pE, mE, dE,
                                    lat1, lat2, acc1, acc2, out_mgcn, out_dgcn);
  k_spmm<2><<<sb, 256, 0, stream>>>(off1, pc1, pv1, off2, pc2, pv2, pE, mE, dE,
                                    lat1, lat2, acc1, acc2, out_mgcn, out_dgcn);

  // ---- 4 GATs: 2 dispatches ----
  k_gat_feat_all<<<FEAT_BLOCKS, 256, 0, stream>>>(acc1, acc2, gat_W, gat_al, gat_ar,
                                                  f0, f1, f2, f3, el, er);
  int ab = ((2 * P + 2 * M) * 64 + 255) / 256;
  k_gat_agg_all<<<ab, 256, 0, stream>>>(og0, ps0, og1, ps1, og2, ps2, og3, ps3,
                                        el, er, f0, f1, f2, f3, gat_b,
                                        e0b, e1b, e2b, e3b);

  // ---- semantic attention: 2 dispatches ----
  k_sem_w_all<<<SEM_BLOCKS, 128, 0, stream>>>(e0b, e1b, e2b, e3b, sa_W1, sa_b1, sa_W2, wbuf);
  int cb = ((P * F + M * F) / 4 + 255) / 256;
  k_sem_comb_all<<<cb, 256, 0, stream>>>(e0b, e1b, e2b, e3b, wbuf, out_pat, out_med);

  // ---- final: simi_pm = M * relu(patient) @ W_top + c ----
  k_cvec<<<1, 256, 0, stream>>>(out_med, out_W, out_b, cbuf);
  k_final<<<P / FIN_R, 256, 0, stream>>>(out_pat, out_W, cbuf, out_simi);
}

// Round 3
// 362.251 us; speedup vs baseline: 2.2181x; 1.0059x over previous
//
#include <hip/hip_runtime.h>
#include <cmath>
#include <cstdint>

// Problem constants (fixed by the reference).
constexpr int P  = 2000, M = 150, DG = 2000, F = 256, H = 4, DH = 64;
constexpr int N1 = P + M;          // 2150
constexpr int N2 = P + DG;         // 4000
constexpr int E1 = 137600, E2 = 256000, EGP = 64000, EGM = 4800;
constexpr int SA_HID = 128;

// Edge-range offsets for the fused build kernel.
constexpr int HO1 = E1, HO2 = E1 + E2, HO3 = HO2 + EGP, HO4 = HO3 + EGP,
              HO5 = HO4 + EGM, HOE = HO5 + EGM;   // 531200 total edges

// ELL capacities. Mean degrees: adj 64, gat 32. Chernoff tail at these caps
// is < 1e-10 per row; the overflow list guarantees correctness regardless.
constexpr int CAP_A = 160;
constexpr int CAP_G = 96;
constexpr int OVF_CAP = 4096;

// ---------------------------------------------------------------------------
// Single-pass ELL build: slot = atomicAdd(cur[row]); store packed payload.
// adj: uint2 {col, val_bits} (one 8B store). gat: uint {src} (one 4B store).
// Rare overflow -> int4 {row, payload, valbits, 0} in per-graph list.
// ---------------------------------------------------------------------------
__global__ __launch_bounds__(256) void k_build(
    const int* __restrict__ a1r, const int* __restrict__ a1c, const float* __restrict__ a1v,
    const int* __restrict__ a2r, const int* __restrict__ a2c, const float* __restrict__ a2v,
    const int* __restrict__ d0, const int* __restrict__ s0,
    const int* __restrict__ d1, const int* __restrict__ s1,
    const int* __restrict__ d2, const int* __restrict__ s2,
    const int* __restrict__ d3, const int* __restrict__ s3,
    int* cur1, uint2* ell1, int* cur2, uint2* ell2,
    int* cu0, unsigned* eg0, int* cu1, unsigned* eg1,
    int* cu2, unsigned* eg2, int* cu3, unsigned* eg3,
    int* __restrict__ ovf_n, int4* __restrict__ ovf) {
  int i = blockIdx.x * 256 + threadIdx.x;
  if (i >= HOE) return;
  if (i < HO1) {
    int r = a1r[i];
    int slot = atomicAdd(&cur1[r], 1);
    uint2 pl = {(unsigned)a1c[i], __float_as_uint(a1v[i])};
    if (slot < CAP_A) ell1[(size_t)r * CAP_A + slot] = pl;
    else { int o = atomicAdd(&ovf_n[0], 1); if (o < OVF_CAP) ovf[0 * OVF_CAP + o] = make_int4(r, (int)pl.x, (int)pl.y, 0); }
  } else if (i < HO2) {
    int j = i - HO1;
    int r = a2r[j];
    int slot = atomicAdd(&cur2[r], 1);
    uint2 pl = {(unsigned)a2c[j], __float_as_uint(a2v[j])};
    if (slot < CAP_A) ell2[(size_t)r * CAP_A + slot] = pl;
    else { int o = atomicAdd(&ovf_n[1], 1); if (o < OVF_CAP) ovf[1 * OVF_CAP + o] = make_int4(r, (int)pl.x, (int)pl.y, 0); }
  } else if (i < HO3) {
    int j = i - HO2; int r = d0[j];
    int slot = atomicAdd(&cu0[r], 1);
    if (slot < CAP_G) eg0[(size_t)r * CAP_G + slot] = (unsigned)s0[j];
    else { int o = atomicAdd(&ovf_n[2], 1); if (o < OVF_CAP) ovf[2 * OVF_CAP + o] = make_int4(r, s0[j], 0, 0); }
  } else if (i < HO4) {
    int j = i - HO3; int r = d1[j];
    int slot = atomicAdd(&cu1[r], 1);
    if (slot < CAP_G) eg1[(size_t)r * CAP_G + slot] = (unsigned)s1[j];
    else { int o = atomicAdd(&ovf_n[3], 1); if (o < OVF_CAP) ovf[3 * OVF_CAP + o] = make_int4(r, s1[j], 0, 0); }
  } else if (i < HO5) {
    int j = i - HO4; int r = d2[j];
    int slot = atomicAdd(&cu2[r], 1);
    if (slot < CAP_G) eg2[(size_t)r * CAP_G + slot] = (unsigned)s2[j];
    else { int o = atomicAdd(&ovf_n[4], 1); if (o < OVF_CAP) ovf[4 * OVF_CAP + o] = make_int4(r, s2[j], 0, 0); }
  } else {
    int j = i - HO5; int r = d3[j];
    int slot = atomicAdd(&cu3[r], 1);
    if (slot < CAP_G) eg3[(size_t)r * CAP_G + slot] = (unsigned)s3[j];
    else { int o = atomicAdd(&ovf_n[5], 1); if (o < OVF_CAP) ovf[5 * OVF_CAP + o] = make_int4(r, s3[j], 0, 0); }
  }
}

// ---------------------------------------------------------------------------
// SPMM: wave-per-row over ELL, float4 per lane (64*16B = full 1KB row),
// unroll-4. LAYER 1: x = embeds, writes lat. LAYER 2: x = lat, writes
// acc = lat + s and the m_gcn/d_gcn output slices. Both graphs per dispatch.
// ---------------------------------------------------------------------------
template<int LAYER>
__global__ __launch_bounds__(256) void k_spmm(
    const int* __restrict__ cur1, const uint2* __restrict__ ell1,
    const int* __restrict__ cur2, const uint2* __restrict__ ell2,
    const int* __restrict__ ovf_n, const int4* __restrict__ ovf,
    const float* __restrict__ pE, const float* __restrict__ mE, const float* __restrict__ dE,
    float* __restrict__ lat1, float* __restrict__ lat2,
    float* __restrict__ acc1, float* __restrict__ acc2,
    float* __restrict__ out_mgcn, float* __restrict__ out_dgcn) {
  int gw = (blockIdx.x * 256 + threadIdx.x) >> 6;
  if (gw >= N1 + N2) return;
  int lane = threadIdx.x & 63;
  bool g2 = gw >= N1;
  int row = g2 ? gw - N1 : gw;
  const uint2* pe = (g2 ? ell2 : ell1) + (size_t)row * CAP_A;
  const float* latin = g2 ? lat2 : lat1;
  const float* tailE = g2 ? dE : mE;
  int deg = (g2 ? cur2 : cur1)[row];
  int dn = deg < CAP_A ? deg : CAP_A;
  int fo = lane << 2;
  float4 s = {0.f, 0.f, 0.f, 0.f};
  auto fetch = [&](int c) -> float4 {
    const float* b;
    if (LAYER == 1) b = (c < P) ? (pE + (size_t)c * F) : (tailE + (size_t)(c - P) * F);
    else            b = latin + (size_t)c * F;
    return *(const float4*)(b + fo);
  };
  int i = 0;
  for (; i + 4 <= dn; i += 4) {
    uint2 m0 = pe[i], m1 = pe[i + 1], m2 = pe[i + 2], m3 = pe[i + 3];
    float v0 = __uint_as_float(m0.y), v1 = __uint_as_float(m1.y),
          v2 = __uint_as_float(m2.y), v3 = __uint_as_float(m3.y);
    float4 a0 = fetch((int)m0.x), a1 = fetch((int)m1.x),
           a2 = fetch((int)m2.x), a3 = fetch((int)m3.x);
    s.x += v0 * a0.x + v1 * a1.x + v2 * a2.x + v3 * a3.x;
    s.y += v0 * a0.y + v1 * a1.y + v2 * a2.y + v3 * a3.y;
    s.z += v0 * a0.z + v1 * a1.z + v2 * a2.z + v3 * a3.z;
    s.w += v0 * a0.w + v1 * a1.w + v2 * a2.w + v3 * a3.w;
  }
  for (; i < dn; ++i) {
    uint2 m = pe[i];
    float v = __uint_as_float(m.y);
    float4 a = fetch((int)m.x);
    s.x += v * a.x; s.y += v * a.y; s.z += v * a.z; s.w += v * a.w;
  }
  // Overflow edges (normally zero).
  {
    int gi = g2 ? 1 : 0;
    int on = ovf_n[gi];
    if (on > 0) {
      const int4* ol = ovf + gi * OVF_CAP;
      for (int k = 0; k < on; ++k) {
        int4 e = ol[k];
        if (e.x == row) {
          float v = __int_as_float(e.z);
          float4 a = fetch(e.y);
          s.x += v * a.x; s.y += v * a.y; s.z += v * a.z; s.w += v * a.w;
        }
      }
    }
  }
  float4 l;
  l.x = s.x > 0.f ? s.x : 0.5f * s.x;
  l.y = s.y > 0.f ? s.y : 0.5f * s.y;
  l.z = s.z > 0.f ? s.z : 0.5f * s.z;
  l.w = s.w > 0.f ? s.w : 0.5f * s.w;
  if (LAYER == 1) {
    *(float4*)((g2 ? lat2 : lat1) + (size_t)row * F + fo) = l;
  } else {
    float4 b = *(const float4*)(latin + (size_t)row * F + fo);  // acc after L1 == lat
    float4 a = {b.x + l.x, b.y + l.y, b.z + l.z, b.w + l.w};
    *(float4*)((g2 ? acc2 : acc1) + (size_t)row * F + fo) = a;
    if (row >= P)
      *(float4*)((g2 ? out_dgcn : out_mgcn) + (size_t)(row - P) * F + fo) = a;
  }
}

// ---------------------------------------------------------------------------
// All 4 GAT feature GEMMs in one dispatch. FR=4 rows/block, float4 LDS reads.
// ---------------------------------------------------------------------------
constexpr int FR  = 4;
constexpr int NB0 = (P + FR - 1) / FR;   // 500
constexpr int NB2 = (M + FR - 1) / FR;   // 38
constexpr int FEAT_BLOCKS = 2 * NB0 + 2 * NB2;

__global__ __launch_bounds__(256) void k_gat_feat_all(
    const float* __restrict__ acc1, const float* __restrict__ acc2,
    const float* __restrict__ gat_W, const float* __restrict__ gat_al,
    const float* __restrict__ gat_ar,
    float* __restrict__ f0, float* __restrict__ f1,
    float* __restrict__ f2, float* __restrict__ f3,
    float* __restrict__ el, float* __restrict__ er) {
  int b = blockIdx.x;
  int g, rb, n; const float* h; float* fout;
  if (b < NB0)            { g = 0; rb = b;              n = P; h = acc1; fout = f0; }
  else if (b < 2 * NB0)   { g = 1; rb = b - NB0;        n = P; h = acc2; fout = f1; }
  else if (b < 2*NB0+NB2) { g = 2; rb = b - 2 * NB0;    n = M; h = acc1 + (size_t)P * F; fout = f2; }
  else                    { g = 3; rb = b - 2*NB0 - NB2; n = M; h = acc1 + (size_t)P * F; fout = f3; }
  int elo = (g == 0) ? 0 : (g == 1) ? P * H : (g == 2) ? 2 * P * H : (2 * P + M) * H;
  const float* W = gat_W + (size_t)g * F * F;
  __shared__ float hs[FR][F];
  int t = threadIdx.x;
  int r0 = rb * FR;
  {
    int r = t >> 6, ln = t & 63;
    int row = r0 + r;
    float4 v = {0.f, 0.f, 0.f, 0.f};
    if (row < n) v = *(const float4*)(h + (size_t)row * F + (ln << 2));
    *(float4*)&hs[r][ln << 2] = v;
  }
  __syncthreads();
  float acc[FR] = {0.f, 0.f, 0.f, 0.f};
  for (int k = 0; k < F; k += 4) {
    float w0 = W[(size_t)k * F + t],       w1 = W[(size_t)(k + 1) * F + t],
          w2 = W[(size_t)(k + 2) * F + t], w3 = W[(size_t)(k + 3) * F + t];
#pragma unroll
    for (int r = 0; r < FR; ++r) {
      float4 h4 = *(const float4*)&hs[r][k];
      acc[r] += h4.x * w0 + h4.y * w1 + h4.z * w2 + h4.w * w3;
    }
  }
  int head = t >> 6, d = t & 63;           // one wave == one head
  float av = gat_al[g * H * DH + head * DH + d];
  float rv = gat_ar[g * H * DH + head * DH + d];
#pragma unroll
  for (int r = 0; r < FR; ++r) {
    int row = r0 + r;
    if (row < n) {
      fout[(size_t)row * F + t] = acc[r];
      float cl = acc[r] * av, cr = acc[r] * rv;
      for (int o = 32; o > 0; o >>= 1) {
        cl += __shfl_down(cl, o, 64);
        cr += __shfl_down(cr, o, 64);
      }
      if (d == 0) { el[elo + row * H + head] = cl; er[elo + row * H + head] = cr; }
    }
  }
}

// ---------------------------------------------------------------------------
// All 4 GAT aggregations in one dispatch: wave-per-dst-row over ELL.
// Fused max + exp-sum + weighted aggregation + bias + ELU.
// ---------------------------------------------------------------------------
__global__ __launch_bounds__(256) void k_gat_agg_all(
    const int* __restrict__ cu0, const unsigned* __restrict__ eg0,
    const int* __restrict__ cu1, const unsigned* __restrict__ eg1,
    const int* __restrict__ cu2, const unsigned* __restrict__ eg2,
    const int* __restrict__ cu3, const unsigned* __restrict__ eg3,
    const int* __restrict__ ovf_n, const int4* __restrict__ ovf,
    const float* __restrict__ el, const float* __restrict__ er,
    const float* __restrict__ f0, const float* __restrict__ f1,
    const float* __restrict__ f2, const float* __restrict__ f3,
    const float* __restrict__ gat_b,
    float* __restrict__ e0, float* __restrict__ e1,
    float* __restrict__ e2, float* __restrict__ e3) {
  int gw = (blockIdx.x * 256 + threadIdx.x) >> 6;
  if (gw >= 2 * P + 2 * M) return;
  int lane = threadIdx.x & 63;
  int g, row; const int* cu; const unsigned* eg; const float* feat; float* out; int elo;
  if (gw < P)            { g = 0; row = gw;             cu = cu0; eg = eg0; feat = f0; out = e0; elo = 0; }
  else if (gw < 2 * P)   { g = 1; row = gw - P;         cu = cu1; eg = eg1; feat = f1; out = e1; elo = P * H; }
  else if (gw < 2*P + M) { g = 2; row = gw - 2 * P;     cu = cu2; eg = eg2; feat = f2; out = e2; elo = 2 * P * H; }
  else                   { g = 3; row = gw - 2 * P - M; cu = cu3; eg = eg3; feat = f3; out = e3; elo = (2 * P + M) * H; }
  int head = lane >> 4;
  int fo = lane << 2;
  const float* elb = el + elo;
  float erv = er[elo + row * H + head];
  int deg = cu[row];
  int dn = deg < CAP_G ? deg : CAP_G;
  const unsigned* ps = eg + (size_t)row * CAP_G;
  int on = ovf_n[2 + g];
  const int4* ol = ovf + (2 + g) * OVF_CAP;
  float mx = -3.4e38f;
  int i = 0;
  for (; i + 4 <= dn; i += 4) {
    int s0 = (int)ps[i], s1 = (int)ps[i + 1], s2 = (int)ps[i + 2], s3 = (int)ps[i + 3];
    float a = elb[s0 * H + head] + erv, b = elb[s1 * H + head] + erv,
          c = elb[s2 * H + head] + erv, d = elb[s3 * H + head] + erv;
    a = a > 0.f ? a : 0.2f * a; b = b > 0.f ? b : 0.2f * b;
    c = c > 0.f ? c : 0.2f * c; d = d > 0.f ? d : 0.2f * d;
    mx = fmaxf(mx, fmaxf(fmaxf(a, b), fmaxf(c, d)));
  }
  for (; i < dn; ++i) {
    float a = elb[(int)ps[i] * H + head] + erv;
    a = a > 0.f ? a : 0.2f * a;
    mx = fmaxf(mx, a);
  }
  if (on > 0) {
    for (int k = 0; k < on; ++k) {
      int4 e = ol[k];
      if (e.x == row) {
        float a = elb[e.y * H + head] + erv;
        a = a > 0.f ? a : 0.2f * a;
        mx = fmaxf(mx, a);
      }
    }
  }
  float ssum = 0.f;
  float4 acc = {0.f, 0.f, 0.f, 0.f};
  i = 0;
  for (; i + 2 <= dn; i += 2) {
    int s0 = (int)ps[i], s1 = (int)ps[i + 1];
    float a = elb[s0 * H + head] + erv; a = a > 0.f ? a : 0.2f * a;
    float b = elb[s1 * H + head] + erv; b = b > 0.f ? b : 0.2f * b;
    float x0 = expf(a - mx), x1 = expf(b - mx);
    float4 q0 = *(const float4*)(feat + (size_t)s0 * F + fo);
    float4 q1 = *(const float4*)(feat + (size_t)s1 * F + fo);
    ssum += x0 + x1;
    acc.x += x0 * q0.x + x1 * q1.x;
    acc.y += x0 * q0.y + x1 * q1.y;
    acc.z += x0 * q0.z + x1 * q1.z;
    acc.w += x0 * q0.w + x1 * q1.w;
  }
  for (; i < dn; ++i) {
    int s0 = (int)ps[i];
    float a = elb[s0 * H + head] + erv; a = a > 0.f ? a : 0.2f * a;
    float x0 = expf(a - mx);
    float4 q0 = *(const float4*)(feat + (size_t)s0 * F + fo);
    ssum += x0;
    acc.x += x0 * q0.x; acc.y += x0 * q0.y; acc.z += x0 * q0.z; acc.w += x0 * q0.w;
  }
  if (on > 0) {
    for (int k = 0; k < on; ++k) {
      int4 e = ol[k];
      if (e.x == row) {
        float a = elb[e.y * H + head] + erv; a = a > 0.f ? a : 0.2f * a;
        float x0 = expf(a - mx);
        float4 q0 = *(const float4*)(feat + (size_t)e.y * F + fo);
        ssum += x0;
        acc.x += x0 * q0.x; acc.y += x0 * q0.y; acc.z += x0 * q0.z; acc.w += x0 * q0.w;
      }
    }
  }
  float inv = 1.f / (ssum + 1e-9f);
  const float* bb = gat_b + g * F + fo;
  float4 v = {acc.x * inv + bb[0], acc.y * inv + bb[1],
              acc.z * inv + bb[2], acc.w * inv + bb[3]};
  v.x = v.x > 0.f ? v.x : expm1f(v.x);
  v.y = v.y > 0.f ? v.y : expm1f(v.y);
  v.z = v.z > 0.f ? v.z : expm1f(v.z);
  v.w = v.w > 0.f ? v.w : expm1f(v.w);
  *(float4*)(out + (size_t)row * F + fo) = v;
}

// ---------------------------------------------------------------------------
// Semantic attention weights for all 4 z-matrices in one dispatch.
// ---------------------------------------------------------------------------
constexpr int SR  = 8;
constexpr int SB0 = (P + SR - 1) / SR;   // 250
constexpr int SB2 = (M + SR - 1) / SR;   // 19
constexpr int SEM_BLOCKS = 2 * SB0 + 2 * SB2;

__global__ __launch_bounds__(128) void k_sem_w_all(
    const float* __restrict__ e0, const float* __restrict__ e1,
    const float* __restrict__ e2, const float* __restrict__ e3,
    const float* __restrict__ W1, const float* __restrict__ b1,
    const float* __restrict__ W2, float* __restrict__ w) {
  int b = blockIdx.x;
  int zid, rb, n; const float* z;
  if (b < SB0)            { zid = 0; rb = b;             n = P; z = e0; }
  else if (b < 2 * SB0)   { zid = 1; rb = b - SB0;       n = P; z = e1; }
  else if (b < 2*SB0+SB2) { zid = 2; rb = b - 2 * SB0;   n = M; z = e2; }
  else                    { zid = 3; rb = b - 2*SB0-SB2; n = M; z = e3; }
  __shared__ float zs[SR][F];
  int t = threadIdx.x;
  int r0 = rb * SR;
  for (int q = t; q < SR * 64; q += 128) {
    int r = q >> 6, ln = q & 63;
    int row = r0 + r;
    float4 v = {0.f, 0.f, 0.f, 0.f};
    if (row < n) v = *(const float4*)(z + (size_t)row * F + (ln << 2));
    *(float4*)&zs[r][ln << 2] = v;
  }
  __syncthreads();
  float hid[SR];
#pragma unroll
  for (int r = 0; r < SR; ++r) hid[r] = b1[t];
  for (int k = 0; k < F; k += 4) {
    float w0 = W1[(size_t)k * SA_HID + t],       w1 = W1[(size_t)(k + 1) * SA_HID + t],
          w2 = W1[(size_t)(k + 2) * SA_HID + t], w3 = W1[(size_t)(k + 3) * SA_HID + t];
#pragma unroll
    for (int r = 0; r < SR; ++r) {
      float4 z4 = *(const float4*)&zs[r][k];
      hid[r] += z4.x * w0 + z4.y * w1 + z4.z * w2 + z4.w * w3;
    }
  }
  float w2v = W2[t];
  float local = 0.f;
  for (int r = 0; r < SR; ++r) {
    int row = r0 + r;
    if (row < n) local += tanhf(hid[r]) * w2v;
  }
  for (int o = 32; o > 0; o >>= 1) local += __shfl_down(local, o, 64);
  __shared__ float pp[2];
  if ((t & 63) == 0) pp[t >> 6] = local;
  __syncthreads();
  if (t == 0) atomicAdd(&w[zid], pp[0] + pp[1]);
}

// ---------------------------------------------------------------------------
// Combine both groups in one dispatch, float4. The LAST block to finish also
// computes c[m2] = (sum_m relu(med[m,:])) . W_bot[:,m2] + M*out_b[m2]
// (device-scope ticket + threadfence; out_med is fully written by then).
// ---------------------------------------------------------------------------
constexpr int Q0 = P * F / 4;       // 128000 float4s (patient)
constexpr int QE = Q0 + M * F / 4;  // + 9600 (med)
constexpr int COMB_BLOCKS = (QE + 255) / 256;

__global__ __launch_bounds__(256) void k_sem_comb_all(
    const float* __restrict__ e0, const float* __restrict__ e1,
    const float* __restrict__ e2, const float* __restrict__ e3,
    const float* __restrict__ w,
    float* __restrict__ out_pat, float* __restrict__ out_med,
    const float* __restrict__ outW, const float* __restrict__ outb,
    float* __restrict__ cbuf, int* __restrict__ done) {
  int i = blockIdx.x * 256 + threadIdx.x;
  if (i < QE) {
    const float4 *z0, *z1; float* out; float inv_n; const float* wp; int j;
    if (i < Q0) { z0 = (const float4*)e0; z1 = (const float4*)e1; out = out_pat; inv_n = 1.f / P; wp = w;     j = i; }
    else        { z0 = (const float4*)e2; z1 = (const float4*)e3; out = out_med; inv_n = 1.f / M; wp = w + 2; j = i - Q0; }
    float m0 = wp[0] * inv_n, m1 = wp[1] * inv_n;
    float mxv = fmaxf(m0, m1);
    float a0 = expf(m0 - mxv), a1 = expf(m1 - mxv);
    float s = 1.f / (a0 + a1);
    a0 *= s; a1 *= s;
    float4 u0 = z0[j], u1 = z1[j];
    float4 r = {a0 * u0.x + a1 * u1.x, a0 * u0.y + a1 * u1.y,
                a0 * u0.z + a1 * u1.z, a0 * u0.w + a1 * u1.w};
    ((float4*)out)[j] = r;
  }
  // Ticket: last block computes cvec.
  __threadfence();
  __syncthreads();
  __shared__ int last;
  if (threadIdx.x == 0) last = (atomicAdd(done, 1) == gridDim.x - 1) ? 1 : 0;
  __syncthreads();
  if (!last) return;
  __threadfence();
  __shared__ float sv[F];
  int t = threadIdx.x;
  float a = 0.f;
  for (int m = 0; m < M; ++m) { float v = out_med[(size_t)m * F + t]; a += v > 0.f ? v : 0.f; }
  sv[t] = a;
  __syncthreads();
  if (t < M) {
    float cc = (float)M * outb[t];
    for (int f = 0; f < F; ++f) cc += sv[f] * outW[(size_t)(F + f) * M + t];
    cbuf[t] = cc;
  }
}

// simi_pm[p,m2] = M * relu(patient[p]) . W_top[:,m2] + c[m2]
constexpr int FIN_R = 8;   // P % FIN_R == 0
__global__ __launch_bounds__(256) void k_final(const float* __restrict__ pat,
                                               const float* __restrict__ outW,
                                               const float* __restrict__ c,
                                               float* __restrict__ simi) {
  __shared__ float psh[FIN_R][F];
  int t = threadIdx.x;
  int r0 = blockIdx.x * FIN_R;
  for (int q = t; q < FIN_R * 64; q += 256) {
    int r = q >> 6, ln = q & 63;
    float4 v = *(const float4*)(pat + (size_t)(r0 + r) * F + (ln << 2));
    v.x = v.x > 0.f ? v.x : 0.f; v.y = v.y > 0.f ? v.y : 0.f;
    v.z = v.z > 0.f ? v.z : 0.f; v.w = v.w > 0.f ? v.w : 0.f;
    *(float4*)&psh[r][ln << 2] = v;
  }
  __syncthreads();
  if (t < M) {
    float acc[FIN_R];
#pragma unroll
    for (int r = 0; r < FIN_R; ++r) acc[r] = 0.f;
    for (int f = 0; f < F; f += 4) {
      float w0 = outW[(size_t)f * M + t],       w1 = outW[(size_t)(f + 1) * M + t],
            w2 = outW[(size_t)(f + 2) * M + t], w3 = outW[(size_t)(f + 3) * M + t];
#pragma unroll
      for (int r = 0; r < FIN_R; ++r) {
        float4 p4 = *(const float4*)&psh[r][f];
        acc[r] += p4.x * w0 + p4.y * w1 + p4.z * w2 + p4.w * w3;
      }
    }
    float cv = c[t];
    for (int r = 0; r < FIN_R; ++r)
      simi[(size_t)(r0 + r) * M + t] = (float)M * acc[r] + cv;
  }
}

// ---------------------------------------------------------------------------
extern "C" void kernel_launch(void* const* d_in, const int* in_sizes, int n_in,
                              void* d_out, int out_size, void* d_ws, size_t ws_size,
                              hipStream_t stream) {
  const int*   adj1_rows = (const int*)d_in[0];
  const int*   adj1_cols = (const int*)d_in[1];
  const float* adj1_vals = (const float*)d_in[2];
  const int*   adj2_rows = (const int*)d_in[3];
  const int*   adj2_cols = (const int*)d_in[4];
  const float* adj2_vals = (const float*)d_in[5];
  const int*   g0_src = (const int*)d_in[6];
  const int*   g0_dst = (const int*)d_in[7];
  const int*   g1_src = (const int*)d_in[8];
  const int*   g1_dst = (const int*)d_in[9];
  const int*   g2_src = (const int*)d_in[10];
  const int*   g2_dst = (const int*)d_in[11];
  const int*   g3_src = (const int*)d_in[12];
  const int*   g3_dst = (const int*)d_in[13];
  // d_in[14] = keepRate (unused, == 1)
  const float* pE     = (const float*)d_in[15];
  const float* mE     = (const float*)d_in[16];
  const float* dE     = (const float*)d_in[17];
  const float* gat_W  = (const float*)d_in[18];
  const float* gat_al = (const float*)d_in[19];
  const float* gat_ar = (const float*)d_in[20];
  const float* gat_b  = (const float*)d_in[21];
  const float* sa_W1  = (const float*)d_in[22];
  const float* sa_b1  = (const float*)d_in[23];
  const float* sa_W2  = (const float*)d_in[24];
  const float* out_W  = (const float*)d_in[25];
  const float* out_b  = (const float*)d_in[26];

  // ---- workspace layout: [zeroed region | ELL | float buffers] ----
  int* ip = (int*)d_ws;
  int* cur1 = ip; ip += N1;
  int* cur2 = ip; ip += N2;
  int* cu0  = ip; ip += P;
  int* cu1  = ip; ip += P;
  int* cu2  = ip; ip += M;
  int* cu3  = ip; ip += M;
  int* ovf_n = ip; ip += 6;
  int* done  = ip; ip += 1;
  float* wbuf = (float*)ip; ip += 4;
  size_t memset_bytes = (size_t)((char*)ip - (char*)d_ws);

  uintptr_t up = ((uintptr_t)ip + 15) & ~(uintptr_t)15;
  int4* ovf = (int4*)up;                       // 6 * OVF_CAP
  uint2* ell1 = (uint2*)(ovf + 6 * OVF_CAP);   // N1 * CAP_A
  uint2* ell2 = ell1 + (size_t)N1 * CAP_A;     // N2 * CAP_A
  unsigned* eg0 = (unsigned*)(ell2 + (size_t)N2 * CAP_A);
  unsigned* eg1 = eg0 + (size_t)P * CAP_G;
  unsigned* eg2 = eg1 + (size_t)P * CAP_G;
  unsigned* eg3 = eg2 + (size_t)M * CAP_G;
  float* fp = (float*)(eg3 + (size_t)M * CAP_G);
  float* lat1 = fp; fp += (size_t)N1 * F;
  float* lat2 = fp; fp += (size_t)N2 * F;
  float* acc1 = fp; fp += (size_t)N1 * F;
  float* acc2 = fp; fp += (size_t)N2 * F;
  float* f0   = fp; fp += (size_t)P * F;
  float* f1   = fp; fp += (size_t)P * F;
  float* f2   = fp; fp += (size_t)M * F;
  float* f3   = fp; fp += (size_t)M * F;
  float* el   = fp; fp += (size_t)(2 * P + 2 * M) * H;
  float* er   = fp; fp += (size_t)(2 * P + 2 * M) * H;
  float* e0b  = fp; fp += (size_t)P * F;
  float* e1b  = fp; fp += (size_t)P * F;
  float* e2b  = fp; fp += (size_t)M * F;
  float* e3b  = fp; fp += (size_t)M * F;
  float* cbuf = fp; fp += 256;

  // ---- output layout: (simi_pm, d_gcn, med, m_gcn, patient) ----
  float* out_simi = (float*)d_out;               // P*M
  float* out_dgcn = out_simi + (size_t)P * M;    // DG*F
  float* out_med  = out_dgcn + (size_t)DG * F;   // M*F
  float* out_mgcn = out_med  + (size_t)M * F;    // M*F
  float* out_pat  = out_mgcn + (size_t)M * F;    // P*F

  // ---- zero counters/tickets (one small contiguous memset) ----
  hipMemsetAsync(d_ws, 0, memset_bytes, stream);

  // ---- ELL build: ONE dispatch (no histogram, no scan) ----
  int eb = (HOE + 255) / 256;
  k_build<<<eb, 256, 0, stream>>>(adj1_rows, adj1_cols, adj1_vals,
                                  adj2_rows, adj2_cols, adj2_vals,
                                  g0_dst, g0_src, g1_dst, g1_src,
                                  g2_dst, g2_src, g3_dst, g3_src,
                                  cur1, ell1, cur2, ell2,
                                  cu0, eg0, cu1, eg1, cu2, eg2, cu3, eg3,
                                  ovf_n, ovf);

  // ---- GNN: 2 fused layers (both graphs per dispatch) ----
  int sb = ((N1 + N2) * 64 + 255) / 256;
  k_spmm<1><<<sb, 256, 0, stream>>>(cur1, ell1, cur2, ell2, ovf_n, ovf, pE, mE, dE,
                                    lat1, lat2, acc1, acc2, out_mgcn, out_dgcn);
  k_spmm<2><<<sb, 256, 0, stream>>>(cur1, ell1, cur2, ell2, ovf_n, ovf, pE, mE, dE,
                                    lat1, lat2, acc1, acc2, out_mgcn, out_dgcn);

  // ---- 4 GATs: 2 dispatches ----
  k_gat_feat_all<<<FEAT_BLOCKS, 256, 0, stream>>>(acc1, acc2, gat_W, gat_al, gat_ar,
                                                  f0, f1, f2, f3, el, er);
  int ab = ((2 * P + 2 * M) * 64 + 255) / 256;
  k_gat_agg_all<<<ab, 256, 0, stream>>>(cu0, eg0, cu1, eg1, cu2, eg2, cu3, eg3,
                                        ovf_n, ovf, el, er, f0, f1, f2, f3, gat_b,
                                        e0b, e1b, e2b, e3b);

  // ---- semantic attention (comb also does cvec in its last block) ----
  k_sem_w_all<<<SEM_BLOCKS, 128, 0, stream>>>(e0b, e1b, e2b, e3b, sa_W1, sa_b1, sa_W2, wbuf);
  k_sem_comb_all<<<COMB_BLOCKS, 256, 0, stream>>>(e0b, e1b, e2b, e3b, wbuf,
                                                  out_pat, out_med, out_W, out_b,
                                                  cbuf, done);

  // ---- final: simi_pm = M * relu(patient) @ W_top + c ----
  k_final<<<P / FIN_R, 256, 0, stream>>>(out_pat, out_W, cbuf, out_simi);
}

// Round 4
// 323.357 us; speedup vs baseline: 2.4849x; 1.1203x over previous
//
#include <hip/hip_runtime.h>
#include <cmath>
#include <cstdint>

// Problem constants (fixed by the reference).
constexpr int P  = 2000, M = 150, DG = 2000, F = 256, H = 4, DH = 64;
constexpr int N1 = P + M;          // 2150
constexpr int N2 = P + DG;         // 4000
constexpr int E1 = 137600, E2 = 256000, EGP = 64000, EGM = 4800;
constexpr int SA_HID = 128;

// Edge-range offsets for the fused build kernel.
constexpr int HO1 = E1, HO2 = E1 + E2, HO3 = HO2 + EGP, HO4 = HO3 + EGP,
              HO5 = HO4 + EGM, HOE = HO5 + EGM;   // 531200 total edges

// ELL capacities. Mean degrees: adj 64, gat 32. Chernoff tail at these caps
// is < 1e-10 per row; the overflow list guarantees correctness regardless.
constexpr int CAP_A = 160;
constexpr int CAP_G = 96;
constexpr int OVF_CAP = 4096;

// ---------------------------------------------------------------------------
// Single-pass ELL build: slot = atomicAdd(cur[row]); store packed payload.
// Grid-stride x4: each thread carries 4 INDEPENDENT edge chains so 4
// device-scope atomics are in flight (the R2 scatter was latency-bound on a
// single atomic->store chain: VALUBusy 0.45%).
// ---------------------------------------------------------------------------
__global__ __launch_bounds__(256) void k_build(
    const int* __restrict__ a1r, const int* __restrict__ a1c, const float* __restrict__ a1v,
    const int* __restrict__ a2r, const int* __restrict__ a2c, const float* __restrict__ a2v,
    const int* __restrict__ d0, const int* __restrict__ s0,
    const int* __restrict__ d1, const int* __restrict__ s1,
    const int* __restrict__ d2, const int* __restrict__ s2,
    const int* __restrict__ d3, const int* __restrict__ s3,
    int* cur1, uint2* ell1, int* cur2, uint2* ell2,
    int* cu0, unsigned* eg0, int* cu1, unsigned* eg1,
    int* cu2, unsigned* eg2, int* cu3, unsigned* eg3,
    int* __restrict__ ovf_n, int4* __restrict__ ovf) {
  int tid = blockIdx.x * 256 + threadIdx.x;
  int T = gridDim.x * 256;
  auto edge = [&](int i) {
    if (i >= HOE) return;
    if (i < HO1) {
      int r = a1r[i];
      int slot = atomicAdd(&cur1[r], 1);
      uint2 pl = {(unsigned)a1c[i], __float_as_uint(a1v[i])};
      if (slot < CAP_A) ell1[(size_t)r * CAP_A + slot] = pl;
      else { int o = atomicAdd(&ovf_n[0], 1); if (o < OVF_CAP) ovf[0 * OVF_CAP + o] = make_int4(r, (int)pl.x, (int)pl.y, 0); }
    } else if (i < HO2) {
      int j = i - HO1;
      int r = a2r[j];
      int slot = atomicAdd(&cur2[r], 1);
      uint2 pl = {(unsigned)a2c[j], __float_as_uint(a2v[j])};
      if (slot < CAP_A) ell2[(size_t)r * CAP_A + slot] = pl;
      else { int o = atomicAdd(&ovf_n[1], 1); if (o < OVF_CAP) ovf[1 * OVF_CAP + o] = make_int4(r, (int)pl.x, (int)pl.y, 0); }
    } else if (i < HO3) {
      int j = i - HO2; int r = d0[j];
      int slot = atomicAdd(&cu0[r], 1);
      if (slot < CAP_G) eg0[(size_t)r * CAP_G + slot] = (unsigned)s0[j];
      else { int o = atomicAdd(&ovf_n[2], 1); if (o < OVF_CAP) ovf[2 * OVF_CAP + o] = make_int4(r, s0[j], 0, 0); }
    } else if (i < HO4) {
      int j = i - HO3; int r = d1[j];
      int slot = atomicAdd(&cu1[r], 1);
      if (slot < CAP_G) eg1[(size_t)r * CAP_G + slot] = (unsigned)s1[j];
      else { int o = atomicAdd(&ovf_n[3], 1); if (o < OVF_CAP) ovf[3 * OVF_CAP + o] = make_int4(r, s1[j], 0, 0); }
    } else if (i < HO5) {
      int j = i - HO4; int r = d2[j];
      int slot = atomicAdd(&cu2[r], 1);
      if (slot < CAP_G) eg2[(size_t)r * CAP_G + slot] = (unsigned)s2[j];
      else { int o = atomicAdd(&ovf_n[4], 1); if (o < OVF_CAP) ovf[4 * OVF_CAP + o] = make_int4(r, s2[j], 0, 0); }
    } else {
      int j = i - HO5; int r = d3[j];
      int slot = atomicAdd(&cu3[r], 1);
      if (slot < CAP_G) eg3[(size_t)r * CAP_G + slot] = (unsigned)s3[j];
      else { int o = atomicAdd(&ovf_n[5], 1); if (o < OVF_CAP) ovf[5 * OVF_CAP + o] = make_int4(r, s3[j], 0, 0); }
    }
  };
  // 4 independent chains per thread.
  edge(tid);
  edge(tid + T);
  edge(tid + 2 * T);
  edge(tid + 3 * T);
}

// ---------------------------------------------------------------------------
// SPMM: wave-per-row over ELL, float4 per lane (64*16B = full 1KB row),
// unroll-4. LAYER 1: x = embeds, writes lat. LAYER 2: x = lat, writes
// acc = lat + s and the m_gcn/d_gcn output slices. Both graphs per dispatch.
// ---------------------------------------------------------------------------
template<int LAYER>
__global__ __launch_bounds__(256) void k_spmm(
    const int* __restrict__ cur1, const uint2* __restrict__ ell1,
    const int* __restrict__ cur2, const uint2* __restrict__ ell2,
    const int* __restrict__ ovf_n, const int4* __restrict__ ovf,
    const float* __restrict__ pE, const float* __restrict__ mE, const float* __restrict__ dE,
    float* __restrict__ lat1, float* __restrict__ lat2,
    float* __restrict__ acc1, float* __restrict__ acc2,
    float* __restrict__ out_mgcn, float* __restrict__ out_dgcn) {
  int gw = (blockIdx.x * 256 + threadIdx.x) >> 6;
  if (gw >= N1 + N2) return;
  int lane = threadIdx.x & 63;
  bool g2 = gw >= N1;
  int row = g2 ? gw - N1 : gw;
  const uint2* pe = (g2 ? ell2 : ell1) + (size_t)row * CAP_A;
  const float* latin = g2 ? lat2 : lat1;
  const float* tailE = g2 ? dE : mE;
  int deg = (g2 ? cur2 : cur1)[row];
  int dn = deg < CAP_A ? deg : CAP_A;
  int fo = lane << 2;
  float4 s = {0.f, 0.f, 0.f, 0.f};
  auto fetch = [&](int c) -> float4 {
    const float* b;
    if (LAYER == 1) b = (c < P) ? (pE + (size_t)c * F) : (tailE + (size_t)(c - P) * F);
    else            b = latin + (size_t)c * F;
    return *(const float4*)(b + fo);
  };
  int i = 0;
  for (; i + 4 <= dn; i += 4) {
    uint2 m0 = pe[i], m1 = pe[i + 1], m2 = pe[i + 2], m3 = pe[i + 3];
    float v0 = __uint_as_float(m0.y), v1 = __uint_as_float(m1.y),
          v2 = __uint_as_float(m2.y), v3 = __uint_as_float(m3.y);
    float4 a0 = fetch((int)m0.x), a1 = fetch((int)m1.x),
           a2 = fetch((int)m2.x), a3 = fetch((int)m3.x);
    s.x += v0 * a0.x + v1 * a1.x + v2 * a2.x + v3 * a3.x;
    s.y += v0 * a0.y + v1 * a1.y + v2 * a2.y + v3 * a3.y;
    s.z += v0 * a0.z + v1 * a1.z + v2 * a2.z + v3 * a3.z;
    s.w += v0 * a0.w + v1 * a1.w + v2 * a2.w + v3 * a3.w;
  }
  for (; i < dn; ++i) {
    uint2 m = pe[i];
    float v = __uint_as_float(m.y);
    float4 a = fetch((int)m.x);
    s.x += v * a.x; s.y += v * a.y; s.z += v * a.z; s.w += v * a.w;
  }
  // Overflow edges (normally zero).
  {
    int gi = g2 ? 1 : 0;
    int on = ovf_n[gi];
    if (on > 0) {
      const int4* ol = ovf + gi * OVF_CAP;
      for (int k = 0; k < on; ++k) {
        int4 e = ol[k];
        if (e.x == row) {
          float v = __int_as_float(e.z);
          float4 a = fetch(e.y);
          s.x += v * a.x; s.y += v * a.y; s.z += v * a.z; s.w += v * a.w;
        }
      }
    }
  }
  float4 l;
  l.x = s.x > 0.f ? s.x : 0.5f * s.x;
  l.y = s.y > 0.f ? s.y : 0.5f * s.y;
  l.z = s.z > 0.f ? s.z : 0.5f * s.z;
  l.w = s.w > 0.f ? s.w : 0.5f * s.w;
  if (LAYER == 1) {
    *(float4*)((g2 ? lat2 : lat1) + (size_t)row * F + fo) = l;
  } else {
    float4 b = *(const float4*)(latin + (size_t)row * F + fo);  // acc after L1 == lat
    float4 a = {b.x + l.x, b.y + l.y, b.z + l.z, b.w + l.w};
    *(float4*)((g2 ? acc2 : acc1) + (size_t)row * F + fo) = a;
    if (row >= P)
      *(float4*)((g2 ? out_dgcn : out_mgcn) + (size_t)(row - P) * F + fo) = a;
  }
}

// ---------------------------------------------------------------------------
// All 4 GAT feature GEMMs in one dispatch. FR=4 rows/block, float4 LDS reads.
// ---------------------------------------------------------------------------
constexpr int FR  = 4;
constexpr int NB0 = (P + FR - 1) / FR;   // 500
constexpr int NB2 = (M + FR - 1) / FR;   // 38
constexpr int FEAT_BLOCKS = 2 * NB0 + 2 * NB2;

__global__ __launch_bounds__(256) void k_gat_feat_all(
    const float* __restrict__ acc1, const float* __restrict__ acc2,
    const float* __restrict__ gat_W, const float* __restrict__ gat_al,
    const float* __restrict__ gat_ar,
    float* __restrict__ f0, float* __restrict__ f1,
    float* __restrict__ f2, float* __restrict__ f3,
    float* __restrict__ el, float* __restrict__ er) {
  int b = blockIdx.x;
  int g, rb, n; const float* h; float* fout;
  if (b < NB0)            { g = 0; rb = b;              n = P; h = acc1; fout = f0; }
  else if (b < 2 * NB0)   { g = 1; rb = b - NB0;        n = P; h = acc2; fout = f1; }
  else if (b < 2*NB0+NB2) { g = 2; rb = b - 2 * NB0;    n = M; h = acc1 + (size_t)P * F; fout = f2; }
  else                    { g = 3; rb = b - 2*NB0 - NB2; n = M; h = acc1 + (size_t)P * F; fout = f3; }
  int elo = (g == 0) ? 0 : (g == 1) ? P * H : (g == 2) ? 2 * P * H : (2 * P + M) * H;
  const float* W = gat_W + (size_t)g * F * F;
  __shared__ float hs[FR][F];
  int t = threadIdx.x;
  int r0 = rb * FR;
  {
    int r = t >> 6, ln = t & 63;
    int row = r0 + r;
    float4 v = {0.f, 0.f, 0.f, 0.f};
    if (row < n) v = *(const float4*)(h + (size_t)row * F + (ln << 2));
    *(float4*)&hs[r][ln << 2] = v;
  }
  __syncthreads();
  float acc[FR] = {0.f, 0.f, 0.f, 0.f};
  for (int k = 0; k < F; k += 4) {
    float w0 = W[(size_t)k * F + t],       w1 = W[(size_t)(k + 1) * F + t],
          w2 = W[(size_t)(k + 2) * F + t], w3 = W[(size_t)(k + 3) * F + t];
#pragma unroll
    for (int r = 0; r < FR; ++r) {
      float4 h4 = *(const float4*)&hs[r][k];
      acc[r] += h4.x * w0 + h4.y * w1 + h4.z * w2 + h4.w * w3;
    }
  }
  int head = t >> 6, d = t & 63;           // one wave == one head
  float av = gat_al[g * H * DH + head * DH + d];
  float rv = gat_ar[g * H * DH + head * DH + d];
#pragma unroll
  for (int r = 0; r < FR; ++r) {
    int row = r0 + r;
    if (row < n) {
      fout[(size_t)row * F + t] = acc[r];
      float cl = acc[r] * av, cr = acc[r] * rv;
      for (int o = 32; o > 0; o >>= 1) {
        cl += __shfl_down(cl, o, 64);
        cr += __shfl_down(cr, o, 64);
      }
      if (d == 0) { el[elo + row * H + head] = cl; er[elo + row * H + head] = cr; }
    }
  }
}

// ---------------------------------------------------------------------------
// All 4 GAT aggregations in one dispatch: wave-per-dst-row over ELL.
// Fused max + exp-sum + weighted aggregation + bias + ELU.
// ---------------------------------------------------------------------------
__global__ __launch_bounds__(256) void k_gat_agg_all(
    const int* __restrict__ cu0, const unsigned* __restrict__ eg0,
    const int* __restrict__ cu1, const unsigned* __restrict__ eg1,
    const int* __restrict__ cu2, const unsigned* __restrict__ eg2,
    const int* __restrict__ cu3, const unsigned* __restrict__ eg3,
    const int* __restrict__ ovf_n, const int4* __restrict__ ovf,
    const float* __restrict__ el, const float* __restrict__ er,
    const float* __restrict__ f0, const float* __restrict__ f1,
    const float* __restrict__ f2, const float* __restrict__ f3,
    const float* __restrict__ gat_b,
    float* __restrict__ e0, float* __restrict__ e1,
    float* __restrict__ e2, float* __restrict__ e3) {
  int gw = (blockIdx.x * 256 + threadIdx.x) >> 6;
  if (gw >= 2 * P + 2 * M) return;
  int lane = threadIdx.x & 63;
  int g, row; const int* cu; const unsigned* eg; const float* feat; float* out; int elo;
  if (gw < P)            { g = 0; row = gw;             cu = cu0; eg = eg0; feat = f0; out = e0; elo = 0; }
  else if (gw < 2 * P)   { g = 1; row = gw - P;         cu = cu1; eg = eg1; feat = f1; out = e1; elo = P * H; }
  else if (gw < 2*P + M) { g = 2; row = gw - 2 * P;     cu = cu2; eg = eg2; feat = f2; out = e2; elo = 2 * P * H; }
  else                   { g = 3; row = gw - 2 * P - M; cu = cu3; eg = eg3; feat = f3; out = e3; elo = (2 * P + M) * H; }
  int head = lane >> 4;
  int fo = lane << 2;
  const float* elb = el + elo;
  float erv = er[elo + row * H + head];
  int deg = cu[row];
  int dn = deg < CAP_G ? deg : CAP_G;
  const unsigned* ps = eg + (size_t)row * CAP_G;
  int on = ovf_n[2 + g];
  const int4* ol = ovf + (2 + g) * OVF_CAP;
  float mx = -3.4e38f;
  int i = 0;
  for (; i + 4 <= dn; i += 4) {
    int s0 = (int)ps[i], s1 = (int)ps[i + 1], s2 = (int)ps[i + 2], s3 = (int)ps[i + 3];
    float a = elb[s0 * H + head] + erv, b = elb[s1 * H + head] + erv,
          c = elb[s2 * H + head] + erv, d = elb[s3 * H + head] + erv;
    a = a > 0.f ? a : 0.2f * a; b = b > 0.f ? b : 0.2f * b;
    c = c > 0.f ? c : 0.2f * c; d = d > 0.f ? d : 0.2f * d;
    mx = fmaxf(mx, fmaxf(fmaxf(a, b), fmaxf(c, d)));
  }
  for (; i < dn; ++i) {
    float a = elb[(int)ps[i] * H + head] + erv;
    a = a > 0.f ? a : 0.2f * a;
    mx = fmaxf(mx, a);
  }
  if (on > 0) {
    for (int k = 0; k < on; ++k) {
      int4 e = ol[k];
      if (e.x == row) {
        float a = elb[e.y * H + head] + erv;
        a = a > 0.f ? a : 0.2f * a;
        mx = fmaxf(mx, a);
      }
    }
  }
  float ssum = 0.f;
  float4 acc = {0.f, 0.f, 0.f, 0.f};
  i = 0;
  for (; i + 2 <= dn; i += 2) {
    int s0 = (int)ps[i], s1 = (int)ps[i + 1];
    float a = elb[s0 * H + head] + erv; a = a > 0.f ? a : 0.2f * a;
    float b = elb[s1 * H + head] + erv; b = b > 0.f ? b : 0.2f * b;
    float x0 = expf(a - mx), x1 = expf(b - mx);
    float4 q0 = *(const float4*)(feat + (size_t)s0 * F + fo);
    float4 q1 = *(const float4*)(feat + (size_t)s1 * F + fo);
    ssum += x0 + x1;
    acc.x += x0 * q0.x + x1 * q1.x;
    acc.y += x0 * q0.y + x1 * q1.y;
    acc.z += x0 * q0.z + x1 * q1.z;
    acc.w += x0 * q0.w + x1 * q1.w;
  }
  for (; i < dn; ++i) {
    int s0 = (int)ps[i];
    float a = elb[s0 * H + head] + erv; a = a > 0.f ? a : 0.2f * a;
    float x0 = expf(a - mx);
    float4 q0 = *(const float4*)(feat + (size_t)s0 * F + fo);
    ssum += x0;
    acc.x += x0 * q0.x; acc.y += x0 * q0.y; acc.z += x0 * q0.z; acc.w += x0 * q0.w;
  }
  if (on > 0) {
    for (int k = 0; k < on; ++k) {
      int4 e = ol[k];
      if (e.x == row) {
        float a = elb[e.y * H + head] + erv; a = a > 0.f ? a : 0.2f * a;
        float x0 = expf(a - mx);
        float4 q0 = *(const float4*)(feat + (size_t)e.y * F + fo);
        ssum += x0;
        acc.x += x0 * q0.x; acc.y += x0 * q0.y; acc.z += x0 * q0.z; acc.w += x0 * q0.w;
      }
    }
  }
  float inv = 1.f / (ssum + 1e-9f);
  const float* bb = gat_b + g * F + fo;
  float4 v = {acc.x * inv + bb[0], acc.y * inv + bb[1],
              acc.z * inv + bb[2], acc.w * inv + bb[3]};
  v.x = v.x > 0.f ? v.x : expm1f(v.x);
  v.y = v.y > 0.f ? v.y : expm1f(v.y);
  v.z = v.z > 0.f ? v.z : expm1f(v.z);
  v.w = v.w > 0.f ? v.w : expm1f(v.w);
  *(float4*)(out + (size_t)row * F + fo) = v;
}

// ---------------------------------------------------------------------------
// Semantic attention weights for all 4 z-matrices in one dispatch.
// ---------------------------------------------------------------------------
constexpr int SR  = 8;
constexpr int SB0 = (P + SR - 1) / SR;   // 250
constexpr int SB2 = (M + SR - 1) / SR;   // 19
constexpr int SEM_BLOCKS = 2 * SB0 + 2 * SB2;

__global__ __launch_bounds__(128) void k_sem_w_all(
    const float* __restrict__ e0, const float* __restrict__ e1,
    const float* __restrict__ e2, const float* __restrict__ e3,
    const float* __restrict__ W1, const float* __restrict__ b1,
    const float* __restrict__ W2, float* __restrict__ w) {
  int b = blockIdx.x;
  int zid, rb, n; const float* z;
  if (b < SB0)            { zid = 0; rb = b;             n = P; z = e0; }
  else if (b < 2 * SB0)   { zid = 1; rb = b - SB0;       n = P; z = e1; }
  else if (b < 2*SB0+SB2) { zid = 2; rb = b - 2 * SB0;   n = M; z = e2; }
  else                    { zid = 3; rb = b - 2*SB0-SB2; n = M; z = e3; }
  __shared__ float zs[SR][F];
  int t = threadIdx.x;
  int r0 = rb * SR;
  for (int q = t; q < SR * 64; q += 128) {
    int r = q >> 6, ln = q & 63;
    int row = r0 + r;
    float4 v = {0.f, 0.f, 0.f, 0.f};
    if (row < n) v = *(const float4*)(z + (size_t)row * F + (ln << 2));
    *(float4*)&zs[r][ln << 2] = v;
  }
  __syncthreads();
  float hid[SR];
#pragma unroll
  for (int r = 0; r < SR; ++r) hid[r] = b1[t];
  for (int k = 0; k < F; k += 4) {
    float w0 = W1[(size_t)k * SA_HID + t],       w1 = W1[(size_t)(k + 1) * SA_HID + t],
          w2 = W1[(size_t)(k + 2) * SA_HID + t], w3 = W1[(size_t)(k + 3) * SA_HID + t];
#pragma unroll
    for (int r = 0; r < SR; ++r) {
      float4 z4 = *(const float4*)&zs[r][k];
      hid[r] += z4.x * w0 + z4.y * w1 + z4.z * w2 + z4.w * w3;
    }
  }
  float w2v = W2[t];
  float local = 0.f;
  for (int r = 0; r < SR; ++r) {
    int row = r0 + r;
    if (row < n) local += tanhf(hid[r]) * w2v;
  }
  for (int o = 32; o > 0; o >>= 1) local += __shfl_down(local, o, 64);
  __shared__ float pp[2];
  if ((t & 63) == 0) pp[t >> 6] = local;
  __syncthreads();
  if (t == 0) atomicAdd(&w[zid], pp[0] + pp[1]);
}

// Combine both groups in one dispatch: out = softmax(w/n) . {z0,z1}, float4.
// (No fence/ticket — the R3 per-block __threadfence cost 68 us.)
__global__ void k_sem_comb_all(const float* __restrict__ e0, const float* __restrict__ e1,
                               const float* __restrict__ e2, const float* __restrict__ e3,
                               const float* __restrict__ w,
                               float* __restrict__ out_pat, float* __restrict__ out_med) {
  constexpr int Q0 = P * F / 4;       // 128000 float4s (patient)
  constexpr int QE = Q0 + M * F / 4;  // + 9600 (med)
  int i = blockIdx.x * 256 + threadIdx.x;
  if (i >= QE) return;
  const float4 *z0, *z1; float* out; float inv_n; const float* wp; int j;
  if (i < Q0) { z0 = (const float4*)e0; z1 = (const float4*)e1; out = out_pat; inv_n = 1.f / P; wp = w;     j = i; }
  else        { z0 = (const float4*)e2; z1 = (const float4*)e3; out = out_med; inv_n = 1.f / M; wp = w + 2; j = i - Q0; }
  float m0 = wp[0] * inv_n, m1 = wp[1] * inv_n;
  float mxv = fmaxf(m0, m1);
  float a0 = expf(m0 - mxv), a1 = expf(m1 - mxv);
  float s = 1.f / (a0 + a1);
  a0 *= s; a1 *= s;
  float4 u0 = z0[j], u1 = z1[j];
  float4 r = {a0 * u0.x + a1 * u1.x, a0 * u0.y + a1 * u1.y,
              a0 * u0.z + a1 * u1.z, a0 * u0.w + a1 * u1.w};
  ((float4*)out)[j] = r;
}

// ---------------------------------------------------------------------------
// c[m2] = (sum_m relu(med[m,:])) . W_bot[:,m2] + M*out_b[m2]   (single block)
// ---------------------------------------------------------------------------
__global__ void k_cvec(const float* __restrict__ med, const float* __restrict__ outW,
                       const float* __restrict__ outb, float* __restrict__ c) {
  __shared__ float sv[F];
  int t = threadIdx.x;  // 256
  float a = 0.f;
  for (int m = 0; m < M; ++m) { float v = med[(size_t)m * F + t]; a += v > 0.f ? v : 0.f; }
  sv[t] = a;
  __syncthreads();
  if (t < M) {
    float cc = (float)M * outb[t];
    for (int f = 0; f < F; ++f) cc += sv[f] * outW[(size_t)(F + f) * M + t];
    c[t] = cc;
  }
}

// simi_pm[p,m2] = M * relu(patient[p]) . W_top[:,m2] + c[m2]
constexpr int FIN_R = 8;   // P % FIN_R == 0
__global__ __launch_bounds__(256) void k_final(const float* __restrict__ pat,
                                               const float* __restrict__ outW,
                                               const float* __restrict__ c,
                                               float* __restrict__ simi) {
  __shared__ float psh[FIN_R][F];
  int t = threadIdx.x;
  int r0 = blockIdx.x * FIN_R;
  for (int q = t; q < FIN_R * 64; q += 256) {
    int r = q >> 6, ln = q & 63;
    float4 v = *(const float4*)(pat + (size_t)(r0 + r) * F + (ln << 2));
    v.x = v.x > 0.f ? v.x : 0.f; v.y = v.y > 0.f ? v.y : 0.f;
    v.z = v.z > 0.f ? v.z : 0.f; v.w = v.w > 0.f ? v.w : 0.f;
    *(float4*)&psh[r][ln << 2] = v;
  }
  __syncthreads();
  if (t < M) {
    float acc[FIN_R];
#pragma unroll
    for (int r = 0; r < FIN_R; ++r) acc[r] = 0.f;
    for (int f = 0; f < F; f += 4) {
      float w0 = outW[(size_t)f * M + t],       w1 = outW[(size_t)(f + 1) * M + t],
            w2 = outW[(size_t)(f + 2) * M + t], w3 = outW[(size_t)(f + 3) * M + t];
#pragma unroll
      for (int r = 0; r < FIN_R; ++r) {
        float4 p4 = *(const float4*)&psh[r][f];
        acc[r] += p4.x * w0 + p4.y * w1 + p4.z * w2 + p4.w * w3;
      }
    }
    float cv = c[t];
    for (int r = 0; r < FIN_R; ++r)
      simi[(size_t)(r0 + r) * M + t] = (float)M * acc[r] + cv;
  }
}

// ---------------------------------------------------------------------------
extern "C" void kernel_launch(void* const* d_in, const int* in_sizes, int n_in,
                              void* d_out, int out_size, void* d_ws, size_t ws_size,
                              hipStream_t stream) {
  const int*   adj1_rows = (const int*)d_in[0];
  const int*   adj1_cols = (const int*)d_in[1];
  const float* adj1_vals = (const float*)d_in[2];
  const int*   adj2_rows = (const int*)d_in[3];
  const int*   adj2_cols = (const int*)d_in[4];
  const float* adj2_vals = (const float*)d_in[5];
  const int*   g0_src = (const int*)d_in[6];
  const int*   g0_dst = (const int*)d_in[7];
  const int*   g1_src = (const int*)d_in[8];
  const int*   g1_dst = (const int*)d_in[9];
  const int*   g2_src = (const int*)d_in[10];
  const int*   g2_dst = (const int*)d_in[11];
  const int*   g3_src = (const int*)d_in[12];
  const int*   g3_dst = (const int*)d_in[13];
  // d_in[14] = keepRate (unused, == 1)
  const float* pE     = (const float*)d_in[15];
  const float* mE     = (const float*)d_in[16];
  const float* dE     = (const float*)d_in[17];
  const float* gat_W  = (const float*)d_in[18];
  const float* gat_al = (const float*)d_in[19];
  const float* gat_ar = (const float*)d_in[20];
  const float* gat_b  = (const float*)d_in[21];
  const float* sa_W1  = (const float*)d_in[22];
  const float* sa_b1  = (const float*)d_in[23];
  const float* sa_W2  = (const float*)d_in[24];
  const float* out_W  = (const float*)d_in[25];
  const float* out_b  = (const float*)d_in[26];

  // ---- workspace layout: [zeroed region | ELL | float buffers] ----
  int* ip = (int*)d_ws;
  int* cur1 = ip; ip += N1;
  int* cur2 = ip; ip += N2;
  int* cu0  = ip; ip += P;
  int* cu1  = ip; ip += P;
  int* cu2  = ip; ip += M;
  int* cu3  = ip; ip += M;
  int* ovf_n = ip; ip += 6;
  float* wbuf = (float*)ip; ip += 4;
  size_t memset_bytes = (size_t)((char*)ip - (char*)d_ws);

  uintptr_t up = ((uintptr_t)ip + 15) & ~(uintptr_t)15;
  int4* ovf = (int4*)up;                       // 6 * OVF_CAP
  uint2* ell1 = (uint2*)(ovf + 6 * OVF_CAP);   // N1 * CAP_A
  uint2* ell2 = ell1 + (size_t)N1 * CAP_A;     // N2 * CAP_A
  unsigned* eg0 = (unsigned*)(ell2 + (size_t)N2 * CAP_A);
  unsigned* eg1 = eg0 + (size_t)P * CAP_G;
  unsigned* eg2 = eg1 + (size_t)P * CAP_G;
  unsigned* eg3 = eg2 + (size_t)M * CAP_G;
  float* fp = (float*)(eg3 + (size_t)M * CAP_G);
  float* lat1 = fp; fp += (size_t)N1 * F;
  float* lat2 = fp; fp += (size_t)N2 * F;
  float* acc1 = fp; fp += (size_t)N1 * F;
  float* acc2 = fp; fp += (size_t)N2 * F;
  float* f0   = fp; fp += (size_t)P * F;
  float* f1   = fp; fp += (size_t)P * F;
  float* f2   = fp; fp += (size_t)M * F;
  float* f3   = fp; fp += (size_t)M * F;
  float* el   = fp; fp += (size_t)(2 * P + 2 * M) * H;
  float* er   = fp; fp += (size_t)(2 * P + 2 * M) * H;
  float* e0b  = fp; fp += (size_t)P * F;
  float* e1b  = fp; fp += (size_t)P * F;
  float* e2b  = fp; fp += (size_t)M * F;
  float* e3b  = fp; fp += (size_t)M * F;
  float* cbuf = fp; fp += 256;

  // ---- output layout: (simi_pm, d_gcn, med, m_gcn, patient) ----
  float* out_simi = (float*)d_out;               // P*M
  float* out_dgcn = out_simi + (size_t)P * M;    // DG*F
  float* out_med  = out_dgcn + (size_t)DG * F;   // M*F
  float* out_mgcn = out_med  + (size_t)M * F;    // M*F
  float* out_pat  = out_mgcn + (size_t)M * F;    // P*F

  // ---- zero counters (one small contiguous memset) ----
  hipMemsetAsync(d_ws, 0, memset_bytes, stream);

  // ---- ELL build: ONE dispatch, 4 edges per thread for atomic ILP ----
  int eb = ((HOE + 3) / 4 + 255) / 256;
  k_build<<<eb, 256, 0, stream>>>(adj1_rows, adj1_cols, adj1_vals,
                                  adj2_rows, adj2_cols, adj2_vals,
                                  g0_dst, g0_src, g1_dst, g1_src,
                                  g2_dst, g2_src, g3_dst, g3_src,
                                  cur1, ell1, cur2, ell2,
                                  cu0, eg0, cu1, eg1, cu2, eg2, cu3, eg3,
                                  ovf_n, ovf);

  // ---- GNN: 2 fused layers (both graphs per dispatch) ----
  int sb = ((N1 + N2) * 64 + 255) / 256;
  k_spmm<1><<<sb, 256, 0, stream>>>(cur1, ell1, cur2, ell2, ovf_n, ovf, pE, mE, dE,
                                    lat1, lat2, acc1, acc2, out_mgcn, out_dgcn);
  k_spmm<2><<<sb, 256, 0, stream>>>(cur1, ell1, cur2, ell2, ovf_n, ovf, pE, mE, dE,
                                    lat1, lat2, acc1, acc2, out_mgcn, out_dgcn);

  // ---- 4 GATs: 2 dispatches ----
  k_gat_feat_all<<<FEAT_BLOCKS, 256, 0, stream>>>(acc1, acc2, gat_W, gat_al, gat_ar,
                                                  f0, f1, f2, f3, el, er);
  int ab = ((2 * P + 2 * M) * 64 + 255) / 256;
  k_gat_agg_all<<<ab, 256, 0, stream>>>(cu0, eg0, cu1, eg1, cu2, eg2, cu3, eg3,
                                        ovf_n, ovf, el, er, f0, f1, f2, f3, gat_b,
                                        e0b, e1b, e2b, e3b);

  // ---- semantic attention: 2 dispatches ----
  k_sem_w_all<<<SEM_BLOCKS, 128, 0, stream>>>(e0b, e1b, e2b, e3b, sa_W1, sa_b1, sa_W2, wbuf);
  int cb = ((P * F + M * F) / 4 + 255) / 256;
  k_sem_comb_all<<<cb, 256, 0, stream>>>(e0b, e1b, e2b, e3b, wbuf, out_pat, out_med);

  // ---- final: simi_pm = M * relu(patient) @ W_top + c ----
  k_cvec<<<1, 256, 0, stream>>>(out_med, out_W, out_b, cbuf);
  k_final<<<P / FIN_R, 256, 0, stream>>>(out_pat, out_W, cbuf, out_simi);
}